// Round 7
// baseline (1072.236 us; speedup 1.0000x reference)
//
#include <hip/hip_runtime.h>
#include <math.h>

#define TPB 256

constexpr int BN_  = 2;
constexpr int CDIM = 128;
constexpr int HH   = 192;
constexpr int WW   = 192;
constexpr int HWc  = HH * WW;      // 36864
constexpr int C3   = 384;
constexpr int HID  = 340;
constexpr int NL2  = 288;          // split-L chunks for QK^T
constexpr int CH2  = HWc / NL2;    // 128
constexpr int CV3  = 576;          // split-L chunks for cov
constexpr int CV3L = HWc / CV3;    // 64

typedef unsigned short bf16_t;
typedef __attribute__((ext_vector_type(8))) __bf16 bf16x8;
typedef __attribute__((ext_vector_type(4))) float f32x4;

__device__ __forceinline__ float b2f(bf16_t v) {
  unsigned u = ((unsigned)v) << 16;
  return __uint_as_float(u);
}
__device__ __forceinline__ bf16_t f2b(float f) {
  unsigned u = __float_as_uint(f);
  unsigned r = (u + 0x7FFFu + ((u >> 16) & 1u)) >> 16;
  return (bf16_t)r;
}
__device__ __forceinline__ float ldf(const float* p) { return *p; }
__device__ __forceinline__ float ldf(const bf16_t* p) { return b2f(*p); }
__device__ __forceinline__ void stf(float* p, float v) { *p = v; }
__device__ __forceinline__ void stf(bf16_t* p, float v) { *p = f2b(v); }

__device__ __forceinline__ float gelu_f(float x) {
  return 0.5f * x * (1.0f + erff(x * 0.7071067811865475f));
}

// unpack uint4 (8 bf16) into rv[1..8]; edges rv[0], rv[9] handled by caller
__device__ __forceinline__ void unpack8(uint4 v, float* rv) {
  unsigned wv[4] = {v.x, v.y, v.z, v.w};
#pragma unroll
  for (int j = 0; j < 8; ++j)
    rv[j + 1] = b2f((bf16_t)((wv[j >> 1] >> ((j & 1) * 16)) & 0xFFFFu));
}
__device__ __forceinline__ uint4 pack8(const float* a) {
  uint4 o;
  unsigned w[4];
#pragma unroll
  for (int p = 0; p < 4; ++p) {
    unsigned lo = f2b(a[2 * p]), hi = f2b(a[2 * p + 1]);
    w[p] = lo | (hi << 16);
  }
  o.x = w[0]; o.y = w[1]; o.z = w[2]; o.w = w[3];
  return o;
}

// ---------------- workspace layout (byte offsets) ----------------
constexpr size_t oATTRAW  = 0;                 // 36,864 B (fp32 2*4608)
constexpr size_t oATTS    = 1327104;           // 36,864 B
constexpr size_t oNORMQ   = 1363968;           // 1024 B
constexpr size_t oNORMK   = 1364992;           // 1024 B
constexpr size_t oIDX     = 1366016;           // 512 B
constexpr size_t oMU      = 1366528;           // 512 B
constexpr size_t oCOV     = 1367040;           // 65,536 B
constexpr size_t oQKV     = 1572864;           // 56,623,104 B (bf16 2*384*36864)
constexpr size_t oXN      = 58195968;          // 18,874,368 B (bf16)  xn / qk-partial / xn2
constexpr size_t oOUTALL  = 77070336;          // 18,874,368 B (bf16)
constexpr size_t oSBUF    = 95944704;          // 18,874,368 B (bf16)
constexpr size_t WS_NEED  = 114819072;
// aliases:
constexpr size_t oCHUNK1  = oOUTALL;                 // 18,874,368 B (128ch qkv chunks)
constexpr size_t oCOVPART = oOUTALL;                 // 37,748,736 B (576*16384 fp32; spans OUTALL+SBUF, both dead)
constexpr size_t oQKPART  = oXN;                     // 5,308,416 B used, xn dead
constexpr size_t oGATED   = oQKV;                    // 18,874,368 B
constexpr size_t oDBUF    = oQKV + 18874368;         // 9,437,184 B
constexpr size_t oY0C     = oOUTALL;                 // 25,067,520 B (spans into oSBUF, both dead)
constexpr size_t oZ       = oQKV;                    // 50,135,040 B

// ---------------- LayerNorm over channel dim (fp32 in, bf16 out) ----------------
__global__ __launch_bounds__(TPB) void k_ln(const float* __restrict__ x,
                                            const float* __restrict__ w,
                                            const float* __restrict__ bias,
                                            bf16_t* __restrict__ out) {
  int t = blockIdx.x * TPB + threadIdx.x;
  if (t >= BN_ * HWc) return;
  int b = t / HWc, l = t - b * HWc;
  const float* xb = x + (size_t)b * CDIM * HWc + l;
  float s = 0.f, s2 = 0.f;
#pragma unroll 4
  for (int c = 0; c < CDIM; ++c) { float v = xb[(size_t)c * HWc]; s += v; s2 += v * v; }
  float mu  = s * (1.f / CDIM);
  float var = s2 * (1.f / CDIM) - mu * mu;
  float inv = 1.f / sqrtf(var + 1e-5f);
  bf16_t* ob = out + (size_t)b * CDIM * HWc + l;
#pragma unroll 4
  for (int c = 0; c < CDIM; ++c)
    stf(&ob[(size_t)c * HWc], (xb[(size_t)c * HWc] - mu) * inv * w[c] + bias[c]);
}

// ---------------- MFMA channel GEMM: out[b,o,l] = sum_c W[o,c] in[b,c,l] ----------------
// 512 threads, 128(O) x 128(L) tile, BK=64. 8 waves in 4(M)x2(N) grid, wave tile 32x64.
// EPI: 0 = (+bias), 1 = (+bias)+aux, 2 = gelu(+bias)*aux
template <typename TO, typename TA, int EPI>
__global__ __launch_bounds__(512) void k_mgemm(const float* __restrict__ W,
                                               const float* __restrict__ bias,
                                               const bf16_t* __restrict__ in,
                                               const TA* __restrict__ aux,
                                               TO* __restrict__ out, int O, int K,
                                               int ibr, int obr, int abr) {
  constexpr int L = HWc;
  constexpr int BM = 128, BN = 128, BK = 64, PK = 72;
  __shared__ bf16_t Wt[BM * PK];   // [o][k]
  __shared__ bf16_t At[BN * PK];   // [l][k]
  int b = blockIdx.z;
  const bf16_t* inb  = in  + (size_t)b * ibr * L;
  const TA*     auxb = aux ? aux + (size_t)b * abr * L : nullptr;
  TO*           outb = out + (size_t)b * obr * L;
  int o0 = blockIdx.y * BM, l0 = blockIdx.x * BN;
  int tid  = threadIdx.x;
  int lane = tid & 63, wid = tid >> 6;       // 8 waves
  int wm = wid >> 1, wn = wid & 1;           // 4x2 wave grid
  int cl = lane & 15, rg = lane >> 4;

  f32x4 acc[2][4];
#pragma unroll
  for (int m = 0; m < 2; ++m)
#pragma unroll
    for (int n = 0; n < 4; ++n) acc[m][n] = (f32x4){0.f, 0.f, 0.f, 0.f};

  for (int k0 = 0; k0 < K; k0 += BK) {
    // ---- stage W tile [BM][BK] fp32 -> bf16, 2048 ushort4 units ----
#pragma unroll
    for (int r = 0; r < 4; ++r) {
      int e = tid + r * 512;
      int o = e >> 4, k4 = (e & 15) * 4;
      int og = o0 + o;
      float w0 = 0.f, w1 = 0.f, w2 = 0.f, w3 = 0.f;
      if (og < O) {
        const float* wp = W + (size_t)og * K + k0 + k4;
        if (k0 + k4 + 0 < K) w0 = wp[0];
        if (k0 + k4 + 1 < K) w1 = wp[1];
        if (k0 + k4 + 2 < K) w2 = wp[2];
        if (k0 + k4 + 3 < K) w3 = wp[3];
      }
      ushort4 pk;
      pk.x = f2b(w0); pk.y = f2b(w1); pk.z = f2b(w2); pk.w = f2b(w3);
      *(ushort4*)(&Wt[o * PK + k4]) = pk;
    }
    // ---- stage act tile transposed: At[l][k] = in[k0+k][l0+l], 512 units ----
    {
      int k2 = tid & 31, lb = tid >> 5;      // lb 0..15
      int ka = k0 + k2 * 2;
      uint4 rowA = {0u, 0u, 0u, 0u}, rowB = {0u, 0u, 0u, 0u};
      if (ka < K)     rowA = *(const uint4*)(&inb[(size_t)ka * L + l0 + lb * 8]);
      if (ka + 1 < K) rowB = *(const uint4*)(&inb[(size_t)(ka + 1) * L + l0 + lb * 8]);
      unsigned wa[4] = {rowA.x, rowA.y, rowA.z, rowA.w};
      unsigned wb[4] = {rowB.x, rowB.y, rowB.z, rowB.w};
#pragma unroll
      for (int j = 0; j < 8; ++j) {
        unsigned va = (wa[j >> 1] >> ((j & 1) * 16)) & 0xFFFFu;
        unsigned vb = (wb[j >> 1] >> ((j & 1) * 16)) & 0xFFFFu;
        *(unsigned*)(&At[(lb * 8 + j) * PK + k2 * 2]) = va | (vb << 16);
      }
    }
    __syncthreads();
#pragma unroll
    for (int kk = 0; kk < 2; ++kk) {
      int kof = kk * 32 + rg * 8;
      bf16x8 a[2], bfr[4];
#pragma unroll
      for (int m = 0; m < 2; ++m)
        a[m] = *(const bf16x8*)(&Wt[(wm * 32 + m * 16 + cl) * PK + kof]);
#pragma unroll
      for (int n = 0; n < 4; ++n)
        bfr[n] = *(const bf16x8*)(&At[(wn * 64 + n * 16 + cl) * PK + kof]);
#pragma unroll
      for (int m = 0; m < 2; ++m)
#pragma unroll
        for (int n = 0; n < 4; ++n)
          acc[m][n] = __builtin_amdgcn_mfma_f32_16x16x32_bf16(a[m], bfr[n], acc[m][n], 0, 0, 0);
    }
    __syncthreads();
  }
#pragma unroll
  for (int m = 0; m < 2; ++m) {
    int obase = o0 + wm * 32 + m * 16 + rg * 4;
#pragma unroll
    for (int n = 0; n < 4; ++n) {
      int col = l0 + wn * 64 + n * 16 + cl;
#pragma unroll
      for (int r = 0; r < 4; ++r) {
        int og = obase + r;
        if (og >= O) continue;
        float v = acc[m][n][r] + (bias ? bias[og] : 0.f);
        size_t off = (size_t)og * L + col;
        if (EPI == 1)      v = v + ldf(&auxb[off]);
        else if (EPI == 2) v = gelu_f(v) * ldf(&auxb[off]);
        stf(&outb[off], v);
      }
    }
  }
}

// ---------------- depthwise 3x3 SAME, vectorized 8 px/thread ----------------
__global__ __launch_bounds__(TPB) void k_dw3v(const bf16_t* __restrict__ in,
                                              const float* __restrict__ wt,
                                              bf16_t* __restrict__ out,
                                              int Cc, int c0, int CoutTotal, long totalG) {
  long t = (long)blockIdx.x * TPB + threadIdx.x;
  if (t >= totalG) return;
  int g = (int)(t % (HWc / 8));
  long bc = t / (HWc / 8);
  int cl = (int)(bc % Cc);
  int b = (int)(bc / Cc);
  int h = g / (WW / 8), w8 = (g % (WW / 8)) * 8;
  const bf16_t* ib = in + ((size_t)b * Cc + cl) * HWc;
  const float* wc = wt + (size_t)(c0 + cl) * 9;
  float rowv[3][10];
#pragma unroll
  for (int dy = -1; dy <= 1; ++dy) {
    float* rv = rowv[dy + 1];
    int hh = h + dy;
    if ((unsigned)hh >= (unsigned)HH) {
#pragma unroll
      for (int j = 0; j < 10; ++j) rv[j] = 0.f;
      continue;
    }
    const bf16_t* rp = ib + hh * WW + w8;
    unpack8(*(const uint4*)rp, rv);
    rv[0] = (w8 > 0) ? b2f(rp[-1]) : 0.f;
    rv[9] = (w8 + 8 < WW) ? b2f(rp[8]) : 0.f;
  }
  float a[8];
#pragma unroll
  for (int j = 0; j < 8; ++j) {
    float s = 0.f;
#pragma unroll
    for (int dy = 0; dy < 3; ++dy)
#pragma unroll
      for (int dx = 0; dx < 3; ++dx)
        s += rowv[dy][j + dx] * wc[dy * 3 + dx];
    a[j] = s;
  }
  *(uint4*)(&out[((size_t)b * CoutTotal + c0 + cl) * HWc + h * WW + w8]) = pack8(a);
}

// ---------------- mu over cf = 0.5*(q_b0+q_b1) ----------------
__global__ __launch_bounds__(TPB) void k_mu(const bf16_t* __restrict__ qkv, float* __restrict__ mu) {
  int c = blockIdx.x;
  __shared__ float red[TPB];
  float s = 0.f;
  for (int l = threadIdx.x; l < HWc; l += TPB)
    s += 0.5f * (b2f(qkv[(size_t)c * HWc + l]) + b2f(qkv[(size_t)C3 * HWc + (size_t)c * HWc + l]));
  red[threadIdx.x] = s;
  __syncthreads();
  for (int st = TPB / 2; st > 0; st >>= 1) {
    if (threadIdx.x < st) red[threadIdx.x] += red[threadIdx.x + st];
    __syncthreads();
  }
  if (threadIdx.x == 0) mu[c] = red[0] / HWc;
}

// ---------------- split-L cov partials (576 chunks x 64 cols, conflict-free) ----------------
__global__ __launch_bounds__(TPB) void k_cov3(const bf16_t* __restrict__ qkv,
                                              float* __restrict__ part) {
  int chunk = blockIdx.x;
  int tid = threadIdx.x, ti = tid & 15, tj = tid >> 4;
  __shared__ float xs[CDIM][65];
  int base = chunk * CV3L;
  // vectorized stage: 1024 uint4-pair units, 4 per thread
#pragma unroll
  for (int r4 = 0; r4 < 4; ++r4) {
    int u = tid + r4 * 256;
    int r = u >> 3, c8 = (u & 7) * 8;
    uint4 vq = *(const uint4*)(&qkv[(size_t)r * HWc + base + c8]);
    uint4 vk = *(const uint4*)(&qkv[(size_t)C3 * HWc + (size_t)r * HWc + base + c8]);
    unsigned wq[4] = {vq.x, vq.y, vq.z, vq.w};
    unsigned wk[4] = {vk.x, vk.y, vk.z, vk.w};
#pragma unroll
    for (int j = 0; j < 8; ++j) {
      float q = b2f((bf16_t)((wq[j >> 1] >> ((j & 1) * 16)) & 0xFFFFu));
      float k = b2f((bf16_t)((wk[j >> 1] >> ((j & 1) * 16)) & 0xFFFFu));
      xs[r][c8 + j] = 0.5f * (q + k);
    }
  }
  __syncthreads();
  float acc[8][8];
#pragma unroll
  for (int m = 0; m < 8; ++m)
#pragma unroll
    for (int n = 0; n < 8; ++n) acc[m][n] = 0.f;
#pragma unroll 2
  for (int l = 0; l < CV3L; ++l) {
    float a[8], b[8];
#pragma unroll
    for (int m = 0; m < 8; ++m) a[m] = xs[ti + 16 * m][l];   // bank = (ti+16m+l)%32: conflict-free
#pragma unroll
    for (int n = 0; n < 8; ++n) b[n] = xs[tj + 16 * n][l];
#pragma unroll
    for (int m = 0; m < 8; ++m)
#pragma unroll
      for (int n = 0; n < 8; ++n) acc[m][n] += a[m] * b[n];
  }
  float* pb = part + (size_t)chunk * CDIM * CDIM;
#pragma unroll
  for (int m = 0; m < 8; ++m)
#pragma unroll
    for (int n = 0; n < 8; ++n)
      pb[(ti + 16 * m) * CDIM + tj + 16 * n] = acc[m][n];
}

// ---------------- reduce cov partials + mean correction ----------------
__global__ __launch_bounds__(TPB) void k_covred(const float* __restrict__ part,
                                                const float* __restrict__ mu,
                                                float* __restrict__ cov) {
  int t = blockIdx.x * TPB + threadIdx.x;
  if (t >= CDIM * CDIM) return;
  float s = 0.f;
  for (int p = 0; p < CV3; ++p) s += part[(size_t)p * CDIM * CDIM + t];
  int c = t >> 7, d = t & 127;
  cov[t] = s - (float)HWc * mu[c] * mu[d];
}

// ---------------- parallel stable rank ----------------
__global__ __launch_bounds__(CDIM) void k_rank(const float* __restrict__ cov,
                                               int* __restrict__ idx) {
  __shared__ float dsd[CDIM], score[CDIM];
  int tid = threadIdx.x;
  dsd[tid] = sqrtf(cov[tid * CDIM + tid]);
  __syncthreads();
  {
    float s = 0.f, di = dsd[tid];
    for (int d = 0; d < CDIM; ++d) s += cov[tid * CDIM + d] / (di * dsd[d]);
    score[tid] = s;
  }
  __syncthreads();
  {
    float my = score[tid];
    int rank = 0;
    for (int d = 0; d < CDIM; ++d)
      rank += (score[d] > my) || (score[d] == my && d < tid);
    idx[rank] = tid;
  }
}

// ---------------- row norms of permuted q,k ----------------
__global__ __launch_bounds__(TPB) void k_norms(const bf16_t* __restrict__ qkv,
                                               const int* __restrict__ idx,
                                               float* __restrict__ normq,
                                               float* __restrict__ normk) {
  int p = blockIdx.x, b = blockIdx.y, which = blockIdx.z;
  int ch = idx[p] + which * CDIM;
  const bf16_t* row = qkv + ((size_t)b * C3 + ch) * HWc;
  __shared__ float red[TPB];
  float s = 0.f;
  for (int l = threadIdx.x; l < HWc; l += TPB) { float v = b2f(row[l]); s += v * v; }
  red[threadIdx.x] = s;
  __syncthreads();
  for (int st = TPB / 2; st > 0; st >>= 1) {
    if (threadIdx.x < st) red[threadIdx.x] += red[threadIdx.x + st];
    __syncthreads();
  }
  if (threadIdx.x == 0) {
    float n = fmaxf(sqrtf(red[0]), 1e-12f);
    (which ? normk : normq)[b * CDIM + p] = n;
  }
}

// ---------------- QK^T split-L partials (288 chunks, vectorized staging) ----------------
template <int G>
__global__ __launch_bounds__(TPB) void k_qk2(const bf16_t* __restrict__ qkv,
                                             const int* __restrict__ idx, int start,
                                             float* __restrict__ partial) {
  constexpr int RT = G / 16;
  constexpr int U  = G * CH2 / 8;
  int nl = blockIdx.x, b = blockIdx.y;
  __shared__ float qs[G][CH2 + 2], ks[G][CH2 + 2];
  __shared__ int idxg[G];
  int tid = threadIdx.x;
  if (tid < G) idxg[tid] = idx[start + tid];
  __syncthreads();
  int l0 = nl * CH2;
  for (int u = tid; u < U; u += TPB) {
    int r = u / (CH2 / 8), c8 = (u % (CH2 / 8)) * 8;
    int ch = idxg[r];
    uint4 vq = *(const uint4*)(&qkv[((size_t)b * C3 + ch) * HWc + l0 + c8]);
    uint4 vk = *(const uint4*)(&qkv[((size_t)b * C3 + CDIM + ch) * HWc + l0 + c8]);
    unsigned wq[4] = {vq.x, vq.y, vq.z, vq.w};
    unsigned wk[4] = {vk.x, vk.y, vk.z, vk.w};
#pragma unroll
    for (int j = 0; j < 8; ++j) {
      qs[r][c8 + j] = b2f((bf16_t)((wq[j >> 1] >> ((j & 1) * 16)) & 0xFFFFu));
      ks[r][c8 + j] = b2f((bf16_t)((wk[j >> 1] >> ((j & 1) * 16)) & 0xFFFFu));
    }
  }
  __syncthreads();
  int ti = tid & 15, tj = tid >> 4;
  float acc[RT][RT];
#pragma unroll
  for (int m = 0; m < RT; ++m)
#pragma unroll
    for (int n = 0; n < RT; ++n) acc[m][n] = 0.f;
#pragma unroll 4
  for (int l = 0; l < CH2; ++l) {
    float qa[RT], kb[RT];
#pragma unroll
    for (int m = 0; m < RT; ++m) qa[m] = qs[ti * RT + m][l];
#pragma unroll
    for (int n = 0; n < RT; ++n) kb[n] = ks[tj * RT + n][l];
#pragma unroll
    for (int m = 0; m < RT; ++m)
#pragma unroll
      for (int n = 0; n < RT; ++n) acc[m][n] += qa[m] * kb[n];
  }
  float* pb = partial + ((size_t)(b * NL2) + nl) * G * G;
#pragma unroll
  for (int m = 0; m < RT; ++m)
#pragma unroll
    for (int n = 0; n < RT; ++n)
      pb[(ti * RT + m) * G + tj * RT + n] = acc[m][n];
}

// ---------------- reduce QK^T partials over chunks ----------------
__global__ __launch_bounds__(TPB) void k_qkred(const float* __restrict__ partial,
                                               float* __restrict__ attraw, int GG) {
  int t = blockIdx.x * TPB + threadIdx.x;
  if (t >= BN_ * GG) return;
  int b = t / GG, e = t - b * GG;
  const float* pb = partial + (size_t)b * NL2 * GG + e;
  float s = 0.f;
  for (int nl = 0; nl < NL2; ++nl) s += pb[(size_t)nl * GG];
  attraw[t] = s;
}

// ---------------- per-group softmax + pooled-cache MLP ----------------
template <int G>
__global__ __launch_bounds__(TPB) void k_inter(const float* __restrict__ attraw,
                                               const float* __restrict__ normq,
                                               const float* __restrict__ normk, int start,
                                               const float* __restrict__ temperature, int gi,
                                               const float* __restrict__ qv_cache,
                                               const float* __restrict__ cw_w,
                                               const float* __restrict__ cw_b,
                                               const float* __restrict__ g_w,
                                               const float* __restrict__ g_b,
                                               float* __restrict__ attF) {
  constexpr int GG = G * G;
  int b = blockIdx.x;
  __shared__ float att[GG], t1[GG], sc[GG], sh[GG], x1p[GG], t2[GG];
  int tid = threadIdx.x;
  float temp = temperature[gi];
  for (int e = tid; e < GG; e += TPB) {
    int i = e / G, j = e % G;
    att[e] = attraw[b * GG + e] * temp /
             (normq[b * CDIM + start + i] * normk[b * CDIM + start + j]);
  }
  __syncthreads();
  if (tid < G) {
    float mx = -3.4e38f;
    for (int j = 0; j < G; ++j) mx = fmaxf(mx, att[tid * G + j]);
    float ssum = 0.f;
    for (int j = 0; j < G; ++j) { float ex = expf(att[tid * G + j] - mx); att[tid * G + j] = ex; ssum += ex; }
    float inv = 1.f / ssum;
    for (int j = 0; j < G; ++j) att[tid * G + j] *= inv;
  }
  __syncthreads();
  for (int e = tid; e < GG; e += TPB) {
    int o = e / G, p = e % G;
    int so = o * CDIM / G, eo = ((o + 1) * CDIM + G - 1) / G;
    int sp = p * CDIM / G, ep = ((p + 1) * CDIM + G - 1) / G;
    float ssum = 0.f;
    for (int i2 = so; i2 < eo; ++i2)
      for (int j2 = sp; j2 < ep; ++j2) ssum += qv_cache[i2 * CDIM + j2];
    t1[e] = ssum / (float)((eo - so) * (ep - sp)) + att[e];
  }
  __syncthreads();
  for (int e = tid; e < 2 * GG; e += TPB) {
    int o = e / G, p = e % G;
    float v = cw_b[o];
    for (int c = 0; c < G; ++c) v += cw_w[o * G + c] * t1[c * G + p];
    if (o < G) sc[o * G + p] = v; else sh[(o - G) * G + p] = v;
  }
  __syncthreads();
  for (int e = tid; e < GG; e += TPB) x1p[e] = att[e] * sc[e] + sh[e];
  __syncthreads();
  for (int e = tid; e < GG; e += TPB) {
    int o = e / G, p = e % G;
    float v = g_b[o];
    for (int c = 0; c < G; ++c) v += g_w[o * G + c] * x1p[c * G + p];
    t2[e] = v;
  }
  __syncthreads();
  for (int e = tid; e < GG; e += TPB)
    attF[(size_t)b * GG + e] = x1p[e] * gelu_f(t2[e]) + att[e];
}

// ---------------- att @ V + (qn+kn) fused ----------------
template <int G>
__global__ __launch_bounds__(TPB) void k_av(const bf16_t* __restrict__ qkv,
                                            const int* __restrict__ idx,
                                            const float* __restrict__ attF,
                                            const float* __restrict__ normq,
                                            const float* __restrict__ normk, int start,
                                            bf16_t* __restrict__ out_all,
                                            bf16_t* __restrict__ s_buf) {
  constexpr int GH = G / 2;
  int b = blockIdx.y;
  int l0 = blockIdx.x * 128;
  __shared__ float vt[G][129];
  __shared__ float attL[G * G];
  __shared__ int idxg[G];
  int tid = threadIdx.x;
  if (tid < G) idxg[tid] = idx[start + tid];
  for (int e = tid; e < G * G; e += TPB) attL[e] = attF[(size_t)b * G * G + e];
  __syncthreads();
  for (int e = tid; e < G * 128; e += TPB) {
    int j = e >> 7, c = e & 127;
    vt[j][c] = b2f(qkv[((size_t)b * C3 + 2 * CDIM + idxg[j]) * HWc + l0 + c]);
  }
  __syncthreads();
  int ll = tid & 127, half = tid >> 7;
  float acc[GH];
#pragma unroll
  for (int i = 0; i < GH; ++i) acc[i] = 0.f;
  for (int j = 0; j < G; ++j) {
    float vv = vt[j][ll];
#pragma unroll
    for (int i = 0; i < GH; ++i) acc[i] += attL[(half * GH + i) * G + j] * vv;
  }
#pragma unroll
  for (int i = 0; i < GH; ++i) {
    int ig = half * GH + i;
    int p = start + ig;
    int ch = idxg[ig];
    float qv = b2f(qkv[((size_t)b * C3 + ch) * HWc + l0 + ll]);
    float kv = b2f(qkv[((size_t)b * C3 + CDIM + ch) * HWc + l0 + ll]);
    float tmp = qv / normq[b * CDIM + p] + kv / normk[b * CDIM + p];
    size_t off = ((size_t)b * CDIM + p) * HWc + l0 + ll;
    stf(&out_all[off], acc[i]);
    stf(&s_buf[off], acc[i] + tmp);
  }
}

// ---------------- qv_new: bilinear upsample + floor + EMA ----------------
__global__ __launch_bounds__(TPB) void k_qvnew(const float* __restrict__ attsF,
                                               const float* __restrict__ qv_cache,
                                               float* __restrict__ out_qv) {
  int t = blockIdx.x * TPB + threadIdx.x;
  if (t >= CDIM * CDIM) return;
  int r = t >> 7, cq = t & 127;
  const int gs[4]   = {16, 32, 32, 48};
  const int base[4] = {0, 512, 2560, 4608};
  float acc = 0.f;
  for (int gi = 0; gi < 4; ++gi) {
    int g = gs[gi], gg = g * g;
    const float* a0 = attsF + base[gi];
    float scale = (float)g / CDIM;
    float fr = (r + 0.5f) * scale - 0.5f;
    float fc = (cq + 0.5f) * scale - 0.5f;
    float flr = floorf(fr), flc = floorf(fc);
    int i0 = (int)flr, j0 = (int)flc;
    float wr = fr - flr, wcw = fc - flc;
    int i0c = max(i0, 0), i1c = min(i0 + 1, g - 1);
    int j0c = max(j0, 0), j1c = min(j0 + 1, g - 1);
    float m00 = 0.5f * (a0[i0c * g + j0c] + a0[gg + i0c * g + j0c]);
    float m01 = 0.5f * (a0[i0c * g + j1c] + a0[gg + i0c * g + j1c]);
    float m10 = 0.5f * (a0[i1c * g + j0c] + a0[gg + i1c * g + j0c]);
    float m11 = 0.5f * (a0[i1c * g + j1c] + a0[gg + i1c * g + j1c]);
    float val = (1.f - wr) * ((1.f - wcw) * m00 + wcw * m01)
              + wr * ((1.f - wcw) * m10 + wcw * m11);
    acc += floorf(val);
  }
  out_qv[t] = qv_cache[t] * 0.9f + acc * 0.1f;
}

// ---------------- ffn: dw3 pair + gelu-gate, vectorized 8 px/thread ----------------
__global__ __launch_bounds__(TPB) void k_dwgeluv(const bf16_t* __restrict__ y0c,
                                                 const float* __restrict__ wt,
                                                 bf16_t* __restrict__ z,
                                                 int Cc, int c0, long totalG) {
  long t = (long)blockIdx.x * TPB + threadIdx.x;
  if (t >= totalG) return;
  int g = (int)(t % (HWc / 8));
  long bc = t / (HWc / 8);
  int cl = (int)(bc % Cc);
  int b = (int)(bc / Cc);
  int h = g / (WW / 8), w8 = (g % (WW / 8)) * 8;
  const bf16_t* i1 = y0c + ((size_t)b * 2 * Cc + cl) * HWc;
  const bf16_t* i2 = y0c + ((size_t)b * 2 * Cc + Cc + cl) * HWc;
  const float* w1 = wt + (size_t)(c0 + cl) * 9;
  const float* w2 = wt + (size_t)(HID + c0 + cl) * 9;
  float r1[3][10], r2[3][10];
#pragma unroll
  for (int dy = -1; dy <= 1; ++dy) {
    float* v1 = r1[dy + 1];
    float* v2 = r2[dy + 1];
    int hh = h + dy;
    if ((unsigned)hh >= (unsigned)HH) {
#pragma unroll
      for (int j = 0; j < 10; ++j) { v1[j] = 0.f; v2[j] = 0.f; }
      continue;
    }
    const bf16_t* p1 = i1 + hh * WW + w8;
    const bf16_t* p2 = i2 + hh * WW + w8;
    unpack8(*(const uint4*)p1, v1);
    unpack8(*(const uint4*)p2, v2);
    bool hasL = (w8 > 0), hasR = (w8 + 8 < WW);
    v1[0] = hasL ? b2f(p1[-1]) : 0.f;
    v1[9] = hasR ? b2f(p1[8]) : 0.f;
    v2[0] = hasL ? b2f(p2[-1]) : 0.f;
    v2[9] = hasR ? b2f(p2[8]) : 0.f;
  }
  float o[8];
#pragma unroll
  for (int j = 0; j < 8; ++j) {
    float a1 = 0.f, a2 = 0.f;
#pragma unroll
    for (int dy = 0; dy < 3; ++dy)
#pragma unroll
      for (int dx = 0; dx < 3; ++dx) {
        a1 += r1[dy][j + dx] * w1[dy * 3 + dx];
        a2 += r2[dy][j + dx] * w2[dy * 3 + dx];
      }
    o[j] = gelu_f(a1) * a2;
  }
  *(uint4*)(&z[((size_t)b * HID + c0 + cl) * HWc + h * WW + w8]) = pack8(o);
}

// ---------------- host ----------------
extern "C" void kernel_launch(void* const* d_in, const int* in_sizes, int n_in,
                              void* d_out, int out_size, void* d_ws, size_t ws_size,
                              hipStream_t stream) {
  if (ws_size < WS_NEED) return;  // workspace insufficient

  const float* x        = (const float*)d_in[0];
  const float* qv_cache = (const float*)d_in[1];
  const float* ln1_w    = (const float*)d_in[2];
  const float* ln1_b    = (const float*)d_in[3];
  const float* ln2_w    = (const float*)d_in[4];
  const float* ln2_b    = (const float*)d_in[5];
  const float* temperature = (const float*)d_in[6];
  const float* w_qkv    = (const float*)d_in[7];
  const float* w_qkv_dw = (const float*)d_in[8];
  const float* w_proj   = (const float*)d_in[9];
  const float* intra_down_w = (const float*)d_in[10];
  const float* intra_down_b = (const float*)d_in[11];
  const float* intra_up_w   = (const float*)d_in[12];
  const float* intra_up_b   = (const float*)d_in[13];
  const float* intra_gate_w = (const float*)d_in[14];
  const float* intra_gate_b = (const float*)d_in[15];
  const float* ffn_in_w  = (const float*)d_in[32];
  const float* ffn_dw_w  = (const float*)d_in[33];
  const float* ffn_out_w = (const float*)d_in[34];

  char* wsb = (char*)d_ws;
  float* out    = (float*)d_out;
  float* out_qv = out + (size_t)BN_ * CDIM * HWc;
  float* x1     = out;

  float*  attraw  = (float*)(wsb + oATTRAW);
  float*  atts    = (float*)(wsb + oATTS);
  float*  normq   = (float*)(wsb + oNORMQ);
  float*  normk   = (float*)(wsb + oNORMK);
  int*    idx     = (int*)(wsb + oIDX);
  float*  mu      = (float*)(wsb + oMU);
  float*  cov     = (float*)(wsb + oCOV);
  bf16_t* qkv     = (bf16_t*)(wsb + oQKV);
  bf16_t* xn      = (bf16_t*)(wsb + oXN);
  bf16_t* out_all = (bf16_t*)(wsb + oOUTALL);
  bf16_t* sbuf    = (bf16_t*)(wsb + oSBUF);
  bf16_t* chunk1  = (bf16_t*)(wsb + oCHUNK1);
  float*  covpart = (float*)(wsb + oCOVPART);
  float*  qkpart  = (float*)(wsb + oQKPART);
  bf16_t* gated   = (bf16_t*)(wsb + oGATED);
  bf16_t* dbuf    = (bf16_t*)(wsb + oDBUF);
  bf16_t* xn2     = (bf16_t*)(wsb + oXN);
  bf16_t* y0c     = (bf16_t*)(wsb + oY0C);
  bf16_t* zbuf    = (bf16_t*)(wsb + oZ);

  const int GX = HWc / 128;  // 288 l-tiles

  // 1. LN1: xn = LN(x)
  k_ln<<<(BN_ * HWc + TPB - 1) / TPB, TPB, 0, stream>>>(x, ln1_w, ln1_b, xn);

  // 2+3. qkv = dw3(c1x1(xn, w_qkv)) in 3 chunks of 128 channels
  for (int ci = 0; ci < 3; ++ci) {
    int c0 = ci * 128;
    k_mgemm<bf16_t, float, 0><<<dim3(GX, 1, BN_), 512, 0, stream>>>(
        w_qkv + (size_t)c0 * CDIM, nullptr, xn, nullptr, chunk1, 128, CDIM, CDIM, 128, 0);
    long totG = (long)BN_ * 128 * (HWc / 8);
    k_dw3v<<<(unsigned)((totG + TPB - 1) / TPB), TPB, 0, stream>>>(
        chunk1, w_qkv_dw, qkv, 128, c0, C3, totG);
  }

  // 4-7. correlation sort
  k_mu<<<CDIM, TPB, 0, stream>>>(qkv, mu);
  k_cov3<<<CV3, TPB, 0, stream>>>(qkv, covpart);
  k_covred<<<(CDIM * CDIM + TPB - 1) / TPB, TPB, 0, stream>>>(covpart, mu, cov);
  k_rank<<<1, CDIM, 0, stream>>>(cov, idx);
  // 8. norms
  k_norms<<<dim3(CDIM, BN_, 2), TPB, 0, stream>>>(qkv, idx, normq, normk);

  // groups (xn dead from here -> qkpart overlays it)
  const int gsz[4]    = {16, 32, 32, 48};
  const int gstart[4] = {0, 16, 48, 80};
  const int abase[4]  = {0, 512, 2560, 4608};
  for (int gi = 0; gi < 4; ++gi) {
    int start = gstart[gi];
    const float* cw_w = (const float*)d_in[16 + 4 * gi];
    const float* cw_b = (const float*)d_in[17 + 4 * gi];
    const float* gw   = (const float*)d_in[18 + 4 * gi];
    const float* gb   = (const float*)d_in[19 + 4 * gi];
    float* attF = atts + abase[gi];
    int GG = gsz[gi] * gsz[gi];
    if (gsz[gi] == 16) {
      k_qk2<16><<<dim3(NL2, BN_), TPB, 0, stream>>>(qkv, idx, start, qkpart);
      k_qkred<<<(BN_ * GG + TPB - 1) / TPB, TPB, 0, stream>>>(qkpart, attraw, GG);
      k_inter<16><<<BN_, TPB, 0, stream>>>(attraw, normq, normk, start, temperature, gi,
                                           qv_cache, cw_w, cw_b, gw, gb, attF);
      k_av<16><<<dim3(HWc / 128, BN_), TPB, 0, stream>>>(qkv, idx, attF, normq, normk, start,
                                                         out_all, sbuf);
    } else if (gsz[gi] == 32) {
      k_qk2<32><<<dim3(NL2, BN_), TPB, 0, stream>>>(qkv, idx, start, qkpart);
      k_qkred<<<(BN_ * GG + TPB - 1) / TPB, TPB, 0, stream>>>(qkpart, attraw, GG);
      k_inter<32><<<BN_, TPB, 0, stream>>>(attraw, normq, normk, start, temperature, gi,
                                           qv_cache, cw_w, cw_b, gw, gb, attF);
      k_av<32><<<dim3(HWc / 128, BN_), TPB, 0, stream>>>(qkv, idx, attF, normq, normk, start,
                                                         out_all, sbuf);
    } else {
      k_qk2<48><<<dim3(NL2, BN_), TPB, 0, stream>>>(qkv, idx, start, qkpart);
      k_qkred<<<(BN_ * GG + TPB - 1) / TPB, TPB, 0, stream>>>(qkpart, attraw, GG);
      k_inter<48><<<BN_, TPB, 0, stream>>>(attraw, normq, normk, start, temperature, gi,
                                           qv_cache, cw_w, cw_b, gw, gb, attF);
      k_av<48><<<dim3(HWc / 128, BN_), TPB, 0, stream>>>(qkv, idx, attF, normq, normk, start,
                                                         out_all, sbuf);
    }
  }
  // qv_new
  k_qvnew<<<(CDIM * CDIM + TPB - 1) / TPB, TPB, 0, stream>>>(atts, qv_cache, out_qv);

  // gated channel-MLP (qkv dead from here)
  k_mgemm<bf16_t, bf16_t, 2><<<dim3(GX, 1, BN_), 512, 0, stream>>>(
      intra_gate_w, intra_gate_b, sbuf, sbuf, gated, CDIM, CDIM, CDIM, CDIM, CDIM);
  k_mgemm<bf16_t, float, 0><<<dim3(GX, 1, BN_), 512, 0, stream>>>(
      intra_down_w, intra_down_b, gated, nullptr, dbuf, CDIM / 2, CDIM, CDIM, CDIM / 2, 0);
  k_mgemm<bf16_t, bf16_t, 1><<<dim3(GX, 1, BN_), 512, 0, stream>>>(
      intra_up_w, intra_up_b, dbuf, out_all, out_all, CDIM, CDIM / 2, CDIM / 2, CDIM, CDIM);
  // x1 = x + proj(out_all)
  k_mgemm<float, float, 1><<<dim3(GX, 1, BN_), 512, 0, stream>>>(
      w_proj, nullptr, out_all, x, x1, CDIM, CDIM, CDIM, CDIM, CDIM);
  // LN2
  k_ln<<<(BN_ * HWc + TPB - 1) / TPB, TPB, 0, stream>>>(x1, ln2_w, ln2_b, xn2);

  // FFN in 4 chunks of 85 channel-pairs
  for (int ci = 0; ci < 4; ++ci) {
    int c0 = ci * 85;
    k_mgemm<bf16_t, float, 0><<<dim3(GX, 1, BN_), 512, 0, stream>>>(
        ffn_in_w + (size_t)c0 * CDIM, nullptr, xn2, nullptr, y0c, 85, CDIM, CDIM, 170, 0);
    k_mgemm<bf16_t, float, 0><<<dim3(GX, 1, BN_), 512, 0, stream>>>(
        ffn_in_w + (size_t)(HID + c0) * CDIM, nullptr, xn2, nullptr,
        y0c + (size_t)85 * HWc, 85, CDIM, CDIM, 170, 0);
    long totG = (long)BN_ * 85 * (HWc / 8);
    k_dwgeluv<<<(unsigned)((totG + TPB - 1) / TPB), TPB, 0, stream>>>(
        y0c, ffn_dw_w, zbuf, 85, c0, totG);
  }
  // out = x1 + c1x1(z, ffn_out_w)
  k_mgemm<float, float, 1><<<dim3(GX, 1, BN_), 512, 0, stream>>>(
      ffn_out_w, nullptr, zbuf, x1, out, CDIM, HID, HID, CDIM, CDIM);
}

// Round 8
// 1003.165 us; speedup vs baseline: 1.0689x; 1.0689x over previous
//
#include <hip/hip_runtime.h>
#include <math.h>

#define TPB 256

constexpr int BN_  = 2;
constexpr int CDIM = 128;
constexpr int HH   = 192;
constexpr int WW   = 192;
constexpr int HWc  = HH * WW;      // 36864
constexpr int C3   = 384;
constexpr int HID  = 340;
constexpr int NL2  = 288;          // split-L chunks for QK^T
constexpr int CH2  = HWc / NL2;    // 128
constexpr int CV3  = 576;          // split-L chunks for cov
constexpr int CV3L = HWc / CV3;    // 64

typedef unsigned short bf16_t;
typedef __attribute__((ext_vector_type(8))) __bf16 bf16x8;
typedef __attribute__((ext_vector_type(4))) float f32x4;

__device__ __forceinline__ float b2f(bf16_t v) {
  unsigned u = ((unsigned)v) << 16;
  return __uint_as_float(u);
}
__device__ __forceinline__ bf16_t f2b(float f) {
  unsigned u = __float_as_uint(f);
  unsigned r = (u + 0x7FFFu + ((u >> 16) & 1u)) >> 16;
  return (bf16_t)r;
}
__device__ __forceinline__ float ldf(const float* p) { return *p; }
__device__ __forceinline__ float ldf(const bf16_t* p) { return b2f(*p); }
__device__ __forceinline__ void stf(float* p, float v) { *p = v; }
__device__ __forceinline__ void stf(bf16_t* p, float v) { *p = f2b(v); }

__device__ __forceinline__ float gelu_f(float x) {
  return 0.5f * x * (1.0f + erff(x * 0.7071067811865475f));
}

__device__ __forceinline__ void unpack8(uint4 v, float* rv) {
  unsigned wv[4] = {v.x, v.y, v.z, v.w};
#pragma unroll
  for (int j = 0; j < 8; ++j)
    rv[j + 1] = b2f((bf16_t)((wv[j >> 1] >> ((j & 1) * 16)) & 0xFFFFu));
}
__device__ __forceinline__ uint4 pack8(const float* a) {
  uint4 o;
  unsigned w[4];
#pragma unroll
  for (int p = 0; p < 4; ++p) {
    unsigned lo = f2b(a[2 * p]), hi = f2b(a[2 * p + 1]);
    w[p] = lo | (hi << 16);
  }
  o.x = w[0]; o.y = w[1]; o.z = w[2]; o.w = w[3];
  return o;
}

// ---------------- workspace layout (byte offsets) ----------------
constexpr size_t oATTRAW  = 0;
constexpr size_t oATTS    = 1327104;
constexpr size_t oNORMQ   = 1363968;
constexpr size_t oNORMK   = 1364992;
constexpr size_t oIDX     = 1366016;
constexpr size_t oMU      = 1366528;
constexpr size_t oCOV     = 1367040;
constexpr size_t oQKV     = 1572864;           // 56,623,104 B (bf16 2*384*36864)
constexpr size_t oXN      = 58195968;          // 18,874,368 B  xn / qk-partial / xn2
constexpr size_t oOUTALL  = 77070336;          // 18,874,368 B
constexpr size_t oSBUF    = 95944704;          // 18,874,368 B
constexpr size_t WS_NEED  = 114819072;
// aliases:
constexpr size_t oCHUNK1  = oOUTALL;
constexpr size_t oCOVPART = oOUTALL;           // 37,748,736 B (spans OUTALL+SBUF, both dead)
constexpr size_t oQKPART  = oXN;
constexpr size_t oGATED   = oQKV;
constexpr size_t oDBUF    = oQKV + 18874368;
constexpr size_t oY0C     = oOUTALL;           // 25,067,520 B (spans into oSBUF, both dead)
constexpr size_t oZ       = oQKV;

// ---------------- LayerNorm over channel dim (fp32 in, bf16 out) ----------------
__global__ __launch_bounds__(TPB) void k_ln(const float* __restrict__ x,
                                            const float* __restrict__ w,
                                            const float* __restrict__ bias,
                                            bf16_t* __restrict__ out) {
  int t = blockIdx.x * TPB + threadIdx.x;
  if (t >= BN_ * HWc) return;
  int b = t / HWc, l = t - b * HWc;
  const float* xb = x + (size_t)b * CDIM * HWc + l;
  float s = 0.f, s2 = 0.f;
#pragma unroll 4
  for (int c = 0; c < CDIM; ++c) { float v = xb[(size_t)c * HWc]; s += v; s2 += v * v; }
  float mu  = s * (1.f / CDIM);
  float var = s2 * (1.f / CDIM) - mu * mu;
  float inv = 1.f / sqrtf(var + 1e-5f);
  bf16_t* ob = out + (size_t)b * CDIM * HWc + l;
#pragma unroll 4
  for (int c = 0; c < CDIM; ++c)
    stf(&ob[(size_t)c * HWc], (xb[(size_t)c * HWc] - mu) * inv * w[c] + bias[c]);
}

// ---------------- MFMA channel GEMM (256 thr, 64x128 tile, reg-dbuf K-loop) --------
// out[b,o,l] = sum_c Wrow(o)[c] in[b,c,l];  Wrow(o) = o<osplit ? W+o*K : W2+(o-osplit)*K
// EPI: 0 = (+bias), 1 = (+bias)+aux, 2 = gelu(+bias)*aux
template <typename TO, typename TA, int EPI>
__global__ __launch_bounds__(TPB) void k_mgemm(const float* __restrict__ W,
                                               const float* __restrict__ W2, int osplit,
                                               const float* __restrict__ bias,
                                               const bf16_t* __restrict__ in,
                                               const TA* __restrict__ aux,
                                               TO* __restrict__ out, int O, int K,
                                               int ibr, int obr, int abr) {
  constexpr int L = HWc;
  constexpr int BM = 64, BN = 128, BK = 64, PK = 72;
  __shared__ bf16_t Wt[BM * PK];   // [o][k]
  __shared__ bf16_t At[BN * PK];   // [l][k]
  int b = blockIdx.z;
  const bf16_t* inb  = in  + (size_t)b * ibr * L;
  const TA*     auxb = aux ? aux + (size_t)b * abr * L : nullptr;
  TO*           outb = out + (size_t)b * obr * L;
  int o0 = blockIdx.x * BM, l0 = blockIdx.y * BN;
  int tid  = threadIdx.x;
  int lane = tid & 63, wid = tid >> 6;
  int wm = wid >> 1, wn = wid & 1;           // 2x2 wave grid, wave tile 32x64
  int cl = lane & 15, rg = lane >> 4;

  float wreg[4][4];
  uint4 areg[2][2];

  // ---- prologue: load k-tile 0 into registers ----
#pragma unroll
  for (int r = 0; r < 4; ++r) {
    int e = tid + r * 256;
    int o = e >> 4, k4 = (e & 15) * 4;
    int og = o0 + o;
#pragma unroll
    for (int j = 0; j < 4; ++j) wreg[r][j] = 0.f;
    if (og < O) {
      const float* wrow = (og < osplit) ? (W + (size_t)og * K)
                                        : (W2 + (size_t)(og - osplit) * K);
#pragma unroll
      for (int j = 0; j < 4; ++j)
        if (k4 + j < K) wreg[r][j] = wrow[k4 + j];
    }
  }
#pragma unroll
  for (int r = 0; r < 2; ++r) {
    int u = tid + r * 256;
    int k2 = u & 31, lb = u >> 5;
    int ka = k2 * 2;
    areg[r][0] = (uint4){0u, 0u, 0u, 0u};
    areg[r][1] = (uint4){0u, 0u, 0u, 0u};
    if (ka < K)     areg[r][0] = *(const uint4*)(&inb[(size_t)ka * L + l0 + lb * 8]);
    if (ka + 1 < K) areg[r][1] = *(const uint4*)(&inb[(size_t)(ka + 1) * L + l0 + lb * 8]);
  }

  f32x4 acc[2][4];
#pragma unroll
  for (int m = 0; m < 2; ++m)
#pragma unroll
    for (int n = 0; n < 4; ++n) acc[m][n] = (f32x4){0.f, 0.f, 0.f, 0.f};

  for (int k0 = 0; k0 < K; k0 += BK) {
    // ---- regs -> LDS ----
#pragma unroll
    for (int r = 0; r < 4; ++r) {
      int e = tid + r * 256;
      int o = e >> 4, k4 = (e & 15) * 4;
      ushort4 pk;
      pk.x = f2b(wreg[r][0]); pk.y = f2b(wreg[r][1]);
      pk.z = f2b(wreg[r][2]); pk.w = f2b(wreg[r][3]);
      *(ushort4*)(&Wt[o * PK + k4]) = pk;
    }
#pragma unroll
    for (int r = 0; r < 2; ++r) {
      int u = tid + r * 256;
      int k2 = u & 31, lb = u >> 5;
      unsigned wa[4] = {areg[r][0].x, areg[r][0].y, areg[r][0].z, areg[r][0].w};
      unsigned wb[4] = {areg[r][1].x, areg[r][1].y, areg[r][1].z, areg[r][1].w};
#pragma unroll
      for (int j = 0; j < 8; ++j) {
        unsigned va = (wa[j >> 1] >> ((j & 1) * 16)) & 0xFFFFu;
        unsigned vb = (wb[j >> 1] >> ((j & 1) * 16)) & 0xFFFFu;
        *(unsigned*)(&At[(lb * 8 + j) * PK + k2 * 2]) = va | (vb << 16);
      }
    }
    __syncthreads();
    // ---- issue next k-tile loads (overlap with MFMA below) ----
    int kn = k0 + BK;
    if (kn < K) {
#pragma unroll
      for (int r = 0; r < 4; ++r) {
        int e = tid + r * 256;
        int o = e >> 4, k4 = (e & 15) * 4;
        int og = o0 + o;
#pragma unroll
        for (int j = 0; j < 4; ++j) wreg[r][j] = 0.f;
        if (og < O) {
          const float* wrow = (og < osplit) ? (W + (size_t)og * K)
                                            : (W2 + (size_t)(og - osplit) * K);
#pragma unroll
          for (int j = 0; j < 4; ++j)
            if (kn + k4 + j < K) wreg[r][j] = wrow[kn + k4 + j];
        }
      }
#pragma unroll
      for (int r = 0; r < 2; ++r) {
        int u = tid + r * 256;
        int k2 = u & 31, lb = u >> 5;
        int ka = kn + k2 * 2;
        areg[r][0] = (uint4){0u, 0u, 0u, 0u};
        areg[r][1] = (uint4){0u, 0u, 0u, 0u};
        if (ka < K)     areg[r][0] = *(const uint4*)(&inb[(size_t)ka * L + l0 + lb * 8]);
        if (ka + 1 < K) areg[r][1] = *(const uint4*)(&inb[(size_t)(ka + 1) * L + l0 + lb * 8]);
      }
    }
    // ---- MFMA on staged tile ----
#pragma unroll
    for (int kk = 0; kk < 2; ++kk) {
      int kof = kk * 32 + rg * 8;
      bf16x8 a[2], bfr[4];
#pragma unroll
      for (int m = 0; m < 2; ++m)
        a[m] = *(const bf16x8*)(&Wt[(wm * 32 + m * 16 + cl) * PK + kof]);
#pragma unroll
      for (int n = 0; n < 4; ++n)
        bfr[n] = *(const bf16x8*)(&At[(wn * 64 + n * 16 + cl) * PK + kof]);
#pragma unroll
      for (int m = 0; m < 2; ++m)
#pragma unroll
        for (int n = 0; n < 4; ++n)
          acc[m][n] = __builtin_amdgcn_mfma_f32_16x16x32_bf16(a[m], bfr[n], acc[m][n], 0, 0, 0);
    }
    __syncthreads();
  }
  // ---- epilogue: C/D layout col=lane&15, row=(lane>>4)*4+reg ----
#pragma unroll
  for (int m = 0; m < 2; ++m) {
    int obase = o0 + wm * 32 + m * 16 + rg * 4;
#pragma unroll
    for (int n = 0; n < 4; ++n) {
      int col = l0 + wn * 64 + n * 16 + cl;
#pragma unroll
      for (int r = 0; r < 4; ++r) {
        int og = obase + r;
        if (og >= O) continue;
        float v = acc[m][n][r] + (bias ? bias[og] : 0.f);
        size_t off = (size_t)og * L + col;
        if (EPI == 1)      v = v + ldf(&auxb[off]);
        else if (EPI == 2) v = gelu_f(v) * ldf(&auxb[off]);
        stf(&outb[off], v);
      }
    }
  }
}

// ---------------- depthwise 3x3 SAME, vectorized 8 px/thread ----------------
__global__ __launch_bounds__(TPB) void k_dw3v(const bf16_t* __restrict__ in,
                                              const float* __restrict__ wt,
                                              bf16_t* __restrict__ out,
                                              int Cc, int c0, int CoutTotal, long totalG) {
  long t = (long)blockIdx.x * TPB + threadIdx.x;
  if (t >= totalG) return;
  int g = (int)(t % (HWc / 8));
  long bc = t / (HWc / 8);
  int cl = (int)(bc % Cc);
  int b = (int)(bc / Cc);
  int h = g / (WW / 8), w8 = (g % (WW / 8)) * 8;
  const bf16_t* ib = in + ((size_t)b * Cc + cl) * HWc;
  const float* wc = wt + (size_t)(c0 + cl) * 9;
  float rowv[3][10];
#pragma unroll
  for (int dy = -1; dy <= 1; ++dy) {
    float* rv = rowv[dy + 1];
    int hh = h + dy;
    if ((unsigned)hh >= (unsigned)HH) {
#pragma unroll
      for (int j = 0; j < 10; ++j) rv[j] = 0.f;
      continue;
    }
    const bf16_t* rp = ib + hh * WW + w8;
    unpack8(*(const uint4*)rp, rv);
    rv[0] = (w8 > 0) ? b2f(rp[-1]) : 0.f;
    rv[9] = (w8 + 8 < WW) ? b2f(rp[8]) : 0.f;
  }
  float a[8];
#pragma unroll
  for (int j = 0; j < 8; ++j) {
    float s = 0.f;
#pragma unroll
    for (int dy = 0; dy < 3; ++dy)
#pragma unroll
      for (int dx = 0; dx < 3; ++dx)
        s += rowv[dy][j + dx] * wc[dy * 3 + dx];
    a[j] = s;
  }
  *(uint4*)(&out[((size_t)b * CoutTotal + c0 + cl) * HWc + h * WW + w8]) = pack8(a);
}

// ---------------- mu over cf = 0.5*(q_b0+q_b1) ----------------
__global__ __launch_bounds__(TPB) void k_mu(const bf16_t* __restrict__ qkv, float* __restrict__ mu) {
  int c = blockIdx.x;
  __shared__ float red[TPB];
  float s = 0.f;
  for (int l = threadIdx.x; l < HWc; l += TPB)
    s += 0.5f * (b2f(qkv[(size_t)c * HWc + l]) + b2f(qkv[(size_t)C3 * HWc + (size_t)c * HWc + l]));
  red[threadIdx.x] = s;
  __syncthreads();
  for (int st = TPB / 2; st > 0; st >>= 1) {
    if (threadIdx.x < st) red[threadIdx.x] += red[threadIdx.x + st];
    __syncthreads();
  }
  if (threadIdx.x == 0) mu[c] = red[0] / HWc;
}

// ---------------- split-L cov partials (576 chunks x 64 cols, conflict-free) --------
__global__ __launch_bounds__(TPB) void k_cov3(const bf16_t* __restrict__ qkv,
                                              float* __restrict__ part) {
  int chunk = blockIdx.x;
  int tid = threadIdx.x, ti = tid & 15, tj = tid >> 4;
  __shared__ float xs[CDIM][65];
  int base = chunk * CV3L;
#pragma unroll
  for (int r4 = 0; r4 < 4; ++r4) {
    int u = tid + r4 * 256;
    int r = u >> 3, c8 = (u & 7) * 8;
    uint4 vq = *(const uint4*)(&qkv[(size_t)r * HWc + base + c8]);
    uint4 vk = *(const uint4*)(&qkv[(size_t)C3 * HWc + (size_t)r * HWc + base + c8]);
    unsigned wq[4] = {vq.x, vq.y, vq.z, vq.w};
    unsigned wk[4] = {vk.x, vk.y, vk.z, vk.w};
#pragma unroll
    for (int j = 0; j < 8; ++j) {
      float q = b2f((bf16_t)((wq[j >> 1] >> ((j & 1) * 16)) & 0xFFFFu));
      float k = b2f((bf16_t)((wk[j >> 1] >> ((j & 1) * 16)) & 0xFFFFu));
      xs[r][c8 + j] = 0.5f * (q + k);
    }
  }
  __syncthreads();
  float acc[8][8];
#pragma unroll
  for (int m = 0; m < 8; ++m)
#pragma unroll
    for (int n = 0; n < 8; ++n) acc[m][n] = 0.f;
#pragma unroll 2
  for (int l = 0; l < CV3L; ++l) {
    float a[8], b[8];
#pragma unroll
    for (int m = 0; m < 8; ++m) a[m] = xs[ti + 16 * m][l];
#pragma unroll
    for (int n = 0; n < 8; ++n) b[n] = xs[tj + 16 * n][l];
#pragma unroll
    for (int m = 0; m < 8; ++m)
#pragma unroll
      for (int n = 0; n < 8; ++n) acc[m][n] += a[m] * b[n];
  }
  float* pb = part + (size_t)chunk * CDIM * CDIM;
#pragma unroll
  for (int m = 0; m < 8; ++m)
#pragma unroll
    for (int n = 0; n < 8; ++n)
      pb[(ti + 16 * m) * CDIM + tj + 16 * n] = acc[m][n];
}

// ---------------- reduce cov partials + mean correction ----------------
__global__ __launch_bounds__(TPB) void k_covred(const float* __restrict__ part,
                                                const float* __restrict__ mu,
                                                float* __restrict__ cov) {
  int t = blockIdx.x * TPB + threadIdx.x;
  if (t >= CDIM * CDIM) return;
  float s = 0.f;
  for (int p = 0; p < CV3; ++p) s += part[(size_t)p * CDIM * CDIM + t];
  int c = t >> 7, d = t & 127;
  cov[t] = s - (float)HWc * mu[c] * mu[d];
}

// ---------------- parallel stable rank ----------------
__global__ __launch_bounds__(CDIM) void k_rank(const float* __restrict__ cov,
                                               int* __restrict__ idx) {
  __shared__ float dsd[CDIM], score[CDIM];
  int tid = threadIdx.x;
  dsd[tid] = sqrtf(cov[tid * CDIM + tid]);
  __syncthreads();
  {
    float s = 0.f, di = dsd[tid];
    for (int d = 0; d < CDIM; ++d) s += cov[tid * CDIM + d] / (di * dsd[d]);
    score[tid] = s;
  }
  __syncthreads();
  {
    float my = score[tid];
    int rank = 0;
    for (int d = 0; d < CDIM; ++d)
      rank += (score[d] > my) || (score[d] == my && d < tid);
    idx[rank] = tid;
  }
}

// ---------------- row norms of permuted q,k ----------------
__global__ __launch_bounds__(TPB) void k_norms(const bf16_t* __restrict__ qkv,
                                               const int* __restrict__ idx,
                                               float* __restrict__ normq,
                                               float* __restrict__ normk) {
  int p = blockIdx.x, b = blockIdx.y, which = blockIdx.z;
  int ch = idx[p] + which * CDIM;
  const bf16_t* row = qkv + ((size_t)b * C3 + ch) * HWc;
  __shared__ float red[TPB];
  float s = 0.f;
  for (int l = threadIdx.x; l < HWc; l += TPB) { float v = b2f(row[l]); s += v * v; }
  red[threadIdx.x] = s;
  __syncthreads();
  for (int st = TPB / 2; st > 0; st >>= 1) {
    if (threadIdx.x < st) red[threadIdx.x] += red[threadIdx.x + st];
    __syncthreads();
  }
  if (threadIdx.x == 0) {
    float n = fmaxf(sqrtf(red[0]), 1e-12f);
    (which ? normk : normq)[b * CDIM + p] = n;
  }
}

// ---------------- QK^T split-L partials ----------------
template <int G>
__global__ __launch_bounds__(TPB) void k_qk2(const bf16_t* __restrict__ qkv,
                                             const int* __restrict__ idx, int start,
                                             float* __restrict__ partial) {
  constexpr int RT = G / 16;
  constexpr int U  = G * CH2 / 8;
  int nl = blockIdx.x, b = blockIdx.y;
  __shared__ float qs[G][CH2 + 2], ks[G][CH2 + 2];
  __shared__ int idxg[G];
  int tid = threadIdx.x;
  if (tid < G) idxg[tid] = idx[start + tid];
  __syncthreads();
  int l0 = nl * CH2;
  for (int u = tid; u < U; u += TPB) {
    int r = u / (CH2 / 8), c8 = (u % (CH2 / 8)) * 8;
    int ch = idxg[r];
    uint4 vq = *(const uint4*)(&qkv[((size_t)b * C3 + ch) * HWc + l0 + c8]);
    uint4 vk = *(const uint4*)(&qkv[((size_t)b * C3 + CDIM + ch) * HWc + l0 + c8]);
    unsigned wq[4] = {vq.x, vq.y, vq.z, vq.w};
    unsigned wk[4] = {vk.x, vk.y, vk.z, vk.w};
#pragma unroll
    for (int j = 0; j < 8; ++j) {
      qs[r][c8 + j] = b2f((bf16_t)((wq[j >> 1] >> ((j & 1) * 16)) & 0xFFFFu));
      ks[r][c8 + j] = b2f((bf16_t)((wk[j >> 1] >> ((j & 1) * 16)) & 0xFFFFu));
    }
  }
  __syncthreads();
  int ti = tid & 15, tj = tid >> 4;
  float acc[RT][RT];
#pragma unroll
  for (int m = 0; m < RT; ++m)
#pragma unroll
    for (int n = 0; n < RT; ++n) acc[m][n] = 0.f;
#pragma unroll 4
  for (int l = 0; l < CH2; ++l) {
    float qa[RT], kb[RT];
#pragma unroll
    for (int m = 0; m < RT; ++m) qa[m] = qs[ti * RT + m][l];
#pragma unroll
    for (int n = 0; n < RT; ++n) kb[n] = ks[tj * RT + n][l];
#pragma unroll
    for (int m = 0; m < RT; ++m)
#pragma unroll
      for (int n = 0; n < RT; ++n) acc[m][n] += qa[m] * kb[n];
  }
  float* pb = partial + ((size_t)(b * NL2) + nl) * G * G;
#pragma unroll
  for (int m = 0; m < RT; ++m)
#pragma unroll
    for (int n = 0; n < RT; ++n)
      pb[(ti * RT + m) * G + tj * RT + n] = acc[m][n];
}

// ---------------- reduce QK^T partials over chunks ----------------
__global__ __launch_bounds__(TPB) void k_qkred(const float* __restrict__ partial,
                                               float* __restrict__ attraw, int GG) {
  int t = blockIdx.x * TPB + threadIdx.x;
  if (t >= BN_ * GG) return;
  int b = t / GG, e = t - b * GG;
  const float* pb = partial + (size_t)b * NL2 * GG + e;
  float s = 0.f;
  for (int nl = 0; nl < NL2; ++nl) s += pb[(size_t)nl * GG];
  attraw[t] = s;
}

// ---------------- per-group softmax + pooled-cache MLP ----------------
template <int G>
__global__ __launch_bounds__(TPB) void k_inter(const float* __restrict__ attraw,
                                               const float* __restrict__ normq,
                                               const float* __restrict__ normk, int start,
                                               const float* __restrict__ temperature, int gi,
                                               const float* __restrict__ qv_cache,
                                               const float* __restrict__ cw_w,
                                               const float* __restrict__ cw_b,
                                               const float* __restrict__ g_w,
                                               const float* __restrict__ g_b,
                                               float* __restrict__ attF) {
  constexpr int GG = G * G;
  int b = blockIdx.x;
  __shared__ float att[GG], t1[GG], sc[GG], sh[GG], x1p[GG], t2[GG];
  int tid = threadIdx.x;
  float temp = temperature[gi];
  for (int e = tid; e < GG; e += TPB) {
    int i = e / G, j = e % G;
    att[e] = attraw[b * GG + e] * temp /
             (normq[b * CDIM + start + i] * normk[b * CDIM + start + j]);
  }
  __syncthreads();
  if (tid < G) {
    float mx = -3.4e38f;
    for (int j = 0; j < G; ++j) mx = fmaxf(mx, att[tid * G + j]);
    float ssum = 0.f;
    for (int j = 0; j < G; ++j) { float ex = expf(att[tid * G + j] - mx); att[tid * G + j] = ex; ssum += ex; }
    float inv = 1.f / ssum;
    for (int j = 0; j < G; ++j) att[tid * G + j] *= inv;
  }
  __syncthreads();
  for (int e = tid; e < GG; e += TPB) {
    int o = e / G, p = e % G;
    int so = o * CDIM / G, eo = ((o + 1) * CDIM + G - 1) / G;
    int sp = p * CDIM / G, ep = ((p + 1) * CDIM + G - 1) / G;
    float ssum = 0.f;
    for (int i2 = so; i2 < eo; ++i2)
      for (int j2 = sp; j2 < ep; ++j2) ssum += qv_cache[i2 * CDIM + j2];
    t1[e] = ssum / (float)((eo - so) * (ep - sp)) + att[e];
  }
  __syncthreads();
  for (int e = tid; e < 2 * GG; e += TPB) {
    int o = e / G, p = e % G;
    float v = cw_b[o];
    for (int c = 0; c < G; ++c) v += cw_w[o * G + c] * t1[c * G + p];
    if (o < G) sc[o * G + p] = v; else sh[(o - G) * G + p] = v;
  }
  __syncthreads();
  for (int e = tid; e < GG; e += TPB) x1p[e] = att[e] * sc[e] + sh[e];
  __syncthreads();
  for (int e = tid; e < GG; e += TPB) {
    int o = e / G, p = e % G;
    float v = g_b[o];
    for (int c = 0; c < G; ++c) v += g_w[o * G + c] * x1p[c * G + p];
    t2[e] = v;
  }
  __syncthreads();
  for (int e = tid; e < GG; e += TPB)
    attF[(size_t)b * GG + e] = x1p[e] * gelu_f(t2[e]) + att[e];
}

// ---------------- att @ V + (qn+kn) fused ----------------
template <int G>
__global__ __launch_bounds__(TPB) void k_av(const bf16_t* __restrict__ qkv,
                                            const int* __restrict__ idx,
                                            const float* __restrict__ attF,
                                            const float* __restrict__ normq,
                                            const float* __restrict__ normk, int start,
                                            bf16_t* __restrict__ out_all,
                                            bf16_t* __restrict__ s_buf) {
  constexpr int GH = G / 2;
  int b = blockIdx.y;
  int l0 = blockIdx.x * 128;
  __shared__ float vt[G][129];
  __shared__ float attL[G * G];
  __shared__ int idxg[G];
  int tid = threadIdx.x;
  if (tid < G) idxg[tid] = idx[start + tid];
  for (int e = tid; e < G * G; e += TPB) attL[e] = attF[(size_t)b * G * G + e];
  __syncthreads();
  for (int e = tid; e < G * 128; e += TPB) {
    int j = e >> 7, c = e & 127;
    vt[j][c] = b2f(qkv[((size_t)b * C3 + 2 * CDIM + idxg[j]) * HWc + l0 + c]);
  }
  __syncthreads();
  int ll = tid & 127, half = tid >> 7;
  float acc[GH];
#pragma unroll
  for (int i = 0; i < GH; ++i) acc[i] = 0.f;
  for (int j = 0; j < G; ++j) {
    float vv = vt[j][ll];
#pragma unroll
    for (int i = 0; i < GH; ++i) acc[i] += attL[(half * GH + i) * G + j] * vv;
  }
#pragma unroll
  for (int i = 0; i < GH; ++i) {
    int ig = half * GH + i;
    int p = start + ig;
    int ch = idxg[ig];
    float qv = b2f(qkv[((size_t)b * C3 + ch) * HWc + l0 + ll]);
    float kv = b2f(qkv[((size_t)b * C3 + CDIM + ch) * HWc + l0 + ll]);
    float tmp = qv / normq[b * CDIM + p] + kv / normk[b * CDIM + p];
    size_t off = ((size_t)b * CDIM + p) * HWc + l0 + ll;
    stf(&out_all[off], acc[i]);
    stf(&s_buf[off], acc[i] + tmp);
  }
}

// ---------------- qv_new: bilinear upsample + floor + EMA ----------------
__global__ __launch_bounds__(TPB) void k_qvnew(const float* __restrict__ attsF,
                                               const float* __restrict__ qv_cache,
                                               float* __restrict__ out_qv) {
  int t = blockIdx.x * TPB + threadIdx.x;
  if (t >= CDIM * CDIM) return;
  int r = t >> 7, cq = t & 127;
  const int gs[4]   = {16, 32, 32, 48};
  const int base[4] = {0, 512, 2560, 4608};
  float acc = 0.f;
  for (int gi = 0; gi < 4; ++gi) {
    int g = gs[gi], gg = g * g;
    const float* a0 = attsF + base[gi];
    float scale = (float)g / CDIM;
    float fr = (r + 0.5f) * scale - 0.5f;
    float fc = (cq + 0.5f) * scale - 0.5f;
    float flr = floorf(fr), flc = floorf(fc);
    int i0 = (int)flr, j0 = (int)flc;
    float wr = fr - flr, wcw = fc - flc;
    int i0c = max(i0, 0), i1c = min(i0 + 1, g - 1);
    int j0c = max(j0, 0), j1c = min(j0 + 1, g - 1);
    float m00 = 0.5f * (a0[i0c * g + j0c] + a0[gg + i0c * g + j0c]);
    float m01 = 0.5f * (a0[i0c * g + j1c] + a0[gg + i0c * g + j1c]);
    float m10 = 0.5f * (a0[i1c * g + j0c] + a0[gg + i1c * g + j0c]);
    float m11 = 0.5f * (a0[i1c * g + j1c] + a0[gg + i1c * g + j1c]);
    float val = (1.f - wr) * ((1.f - wcw) * m00 + wcw * m01)
              + wr * ((1.f - wcw) * m10 + wcw * m11);
    acc += floorf(val);
  }
  out_qv[t] = qv_cache[t] * 0.9f + acc * 0.1f;
}

// ---------------- ffn: dw3 pair + gelu-gate, vectorized 8 px/thread ----------------
__global__ __launch_bounds__(TPB) void k_dwgeluv(const bf16_t* __restrict__ y0c,
                                                 const float* __restrict__ wt,
                                                 bf16_t* __restrict__ z,
                                                 int Cc, int c0, long totalG) {
  long t = (long)blockIdx.x * TPB + threadIdx.x;
  if (t >= totalG) return;
  int g = (int)(t % (HWc / 8));
  long bc = t / (HWc / 8);
  int cl = (int)(bc % Cc);
  int b = (int)(bc / Cc);
  int h = g / (WW / 8), w8 = (g % (WW / 8)) * 8;
  const bf16_t* i1 = y0c + ((size_t)b * 2 * Cc + cl) * HWc;
  const bf16_t* i2 = y0c + ((size_t)b * 2 * Cc + Cc + cl) * HWc;
  const float* w1 = wt + (size_t)(c0 + cl) * 9;
  const float* w2 = wt + (size_t)(HID + c0 + cl) * 9;
  float r1[3][10], r2[3][10];
#pragma unroll
  for (int dy = -1; dy <= 1; ++dy) {
    float* v1 = r1[dy + 1];
    float* v2 = r2[dy + 1];
    int hh = h + dy;
    if ((unsigned)hh >= (unsigned)HH) {
#pragma unroll
      for (int j = 0; j < 10; ++j) { v1[j] = 0.f; v2[j] = 0.f; }
      continue;
    }
    const bf16_t* p1 = i1 + hh * WW + w8;
    const bf16_t* p2 = i2 + hh * WW + w8;
    unpack8(*(const uint4*)p1, v1);
    unpack8(*(const uint4*)p2, v2);
    bool hasL = (w8 > 0), hasR = (w8 + 8 < WW);
    v1[0] = hasL ? b2f(p1[-1]) : 0.f;
    v1[9] = hasR ? b2f(p1[8]) : 0.f;
    v2[0] = hasL ? b2f(p2[-1]) : 0.f;
    v2[9] = hasR ? b2f(p2[8]) : 0.f;
  }
  float o[8];
#pragma unroll
  for (int j = 0; j < 8; ++j) {
    float a1 = 0.f, a2 = 0.f;
#pragma unroll
    for (int dy = 0; dy < 3; ++dy)
#pragma unroll
      for (int dx = 0; dx < 3; ++dx) {
        a1 += r1[dy][j + dx] * w1[dy * 3 + dx];
        a2 += r2[dy][j + dx] * w2[dy * 3 + dx];
      }
    o[j] = gelu_f(a1) * a2;
  }
  *(uint4*)(&z[((size_t)b * HID + c0 + cl) * HWc + h * WW + w8]) = pack8(o);
}

// ---------------- host ----------------
extern "C" void kernel_launch(void* const* d_in, const int* in_sizes, int n_in,
                              void* d_out, int out_size, void* d_ws, size_t ws_size,
                              hipStream_t stream) {
  if (ws_size < WS_NEED) return;  // workspace insufficient

  const float* x        = (const float*)d_in[0];
  const float* qv_cache = (const float*)d_in[1];
  const float* ln1_w    = (const float*)d_in[2];
  const float* ln1_b    = (const float*)d_in[3];
  const float* ln2_w    = (const float*)d_in[4];
  const float* ln2_b    = (const float*)d_in[5];
  const float* temperature = (const float*)d_in[6];
  const float* w_qkv    = (const float*)d_in[7];
  const float* w_qkv_dw = (const float*)d_in[8];
  const float* w_proj   = (const float*)d_in[9];
  const float* intra_down_w = (const float*)d_in[10];
  const float* intra_down_b = (const float*)d_in[11];
  const float* intra_up_w   = (const float*)d_in[12];
  const float* intra_up_b   = (const float*)d_in[13];
  const float* intra_gate_w = (const float*)d_in[14];
  const float* intra_gate_b = (const float*)d_in[15];
  const float* ffn_in_w  = (const float*)d_in[32];
  const float* ffn_dw_w  = (const float*)d_in[33];
  const float* ffn_out_w = (const float*)d_in[34];

  char* wsb = (char*)d_ws;
  float* out    = (float*)d_out;
  float* out_qv = out + (size_t)BN_ * CDIM * HWc;
  float* x1     = out;

  float*  attraw  = (float*)(wsb + oATTRAW);
  float*  atts    = (float*)(wsb + oATTS);
  float*  normq   = (float*)(wsb + oNORMQ);
  float*  normk   = (float*)(wsb + oNORMK);
  int*    idx     = (int*)(wsb + oIDX);
  float*  mu      = (float*)(wsb + oMU);
  float*  cov     = (float*)(wsb + oCOV);
  bf16_t* qkv     = (bf16_t*)(wsb + oQKV);
  bf16_t* xn      = (bf16_t*)(wsb + oXN);
  bf16_t* out_all = (bf16_t*)(wsb + oOUTALL);
  bf16_t* sbuf    = (bf16_t*)(wsb + oSBUF);
  bf16_t* chunk1  = (bf16_t*)(wsb + oCHUNK1);
  float*  covpart = (float*)(wsb + oCOVPART);
  float*  qkpart  = (float*)(wsb + oQKPART);
  bf16_t* gated   = (bf16_t*)(wsb + oGATED);
  bf16_t* dbuf    = (bf16_t*)(wsb + oDBUF);
  bf16_t* xn2     = (bf16_t*)(wsb + oXN);
  bf16_t* y0c     = (bf16_t*)(wsb + oY0C);
  bf16_t* zbuf    = (bf16_t*)(wsb + oZ);

  const int GX = HWc / 128;  // 288 l-tiles
  const int NOS = 1 << 30;   // "no osplit"

  // 1. LN1: xn = LN(x)
  k_ln<<<(BN_ * HWc + TPB - 1) / TPB, TPB, 0, stream>>>(x, ln1_w, ln1_b, xn);

  // 2+3. qkv = dw3(c1x1(xn, w_qkv)) in 3 chunks of 128 channels
  for (int ci = 0; ci < 3; ++ci) {
    int c0 = ci * 128;
    k_mgemm<bf16_t, float, 0><<<dim3(2, GX, BN_), TPB, 0, stream>>>(
        w_qkv + (size_t)c0 * CDIM, w_qkv, NOS, nullptr, xn, nullptr, chunk1,
        128, CDIM, CDIM, 128, 0);
    long totG = (long)BN_ * 128 * (HWc / 8);
    k_dw3v<<<(unsigned)((totG + TPB - 1) / TPB), TPB, 0, stream>>>(
        chunk1, w_qkv_dw, qkv, 128, c0, C3, totG);
  }

  // 4-7. correlation sort
  k_mu<<<CDIM, TPB, 0, stream>>>(qkv, mu);
  k_cov3<<<CV3, TPB, 0, stream>>>(qkv, covpart);
  k_covred<<<(CDIM * CDIM + TPB - 1) / TPB, TPB, 0, stream>>>(covpart, mu, cov);
  k_rank<<<1, CDIM, 0, stream>>>(cov, idx);
  // 8. norms
  k_norms<<<dim3(CDIM, BN_, 2), TPB, 0, stream>>>(qkv, idx, normq, normk);

  // groups (xn dead from here -> qkpart overlays it)
  const int gsz[4]    = {16, 32, 32, 48};
  const int gstart[4] = {0, 16, 48, 80};
  const int abase[4]  = {0, 512, 2560, 4608};
  for (int gi = 0; gi < 4; ++gi) {
    int start = gstart[gi];
    const float* cw_w = (const float*)d_in[16 + 4 * gi];
    const float* cw_b = (const float*)d_in[17 + 4 * gi];
    const float* gw   = (const float*)d_in[18 + 4 * gi];
    const float* gb   = (const float*)d_in[19 + 4 * gi];
    float* attF = atts + abase[gi];
    int GG = gsz[gi] * gsz[gi];
    if (gsz[gi] == 16) {
      k_qk2<16><<<dim3(NL2, BN_), TPB, 0, stream>>>(qkv, idx, start, qkpart);
      k_qkred<<<(BN_ * GG + TPB - 1) / TPB, TPB, 0, stream>>>(qkpart, attraw, GG);
      k_inter<16><<<BN_, TPB, 0, stream>>>(attraw, normq, normk, start, temperature, gi,
                                           qv_cache, cw_w, cw_b, gw, gb, attF);
      k_av<16><<<dim3(HWc / 128, BN_), TPB, 0, stream>>>(qkv, idx, attF, normq, normk, start,
                                                         out_all, sbuf);
    } else if (gsz[gi] == 32) {
      k_qk2<32><<<dim3(NL2, BN_), TPB, 0, stream>>>(qkv, idx, start, qkpart);
      k_qkred<<<(BN_ * GG + TPB - 1) / TPB, TPB, 0, stream>>>(qkpart, attraw, GG);
      k_inter<32><<<BN_, TPB, 0, stream>>>(attraw, normq, normk, start, temperature, gi,
                                           qv_cache, cw_w, cw_b, gw, gb, attF);
      k_av<32><<<dim3(HWc / 128, BN_), TPB, 0, stream>>>(qkv, idx, attF, normq, normk, start,
                                                         out_all, sbuf);
    } else {
      k_qk2<48><<<dim3(NL2, BN_), TPB, 0, stream>>>(qkv, idx, start, qkpart);
      k_qkred<<<(BN_ * GG + TPB - 1) / TPB, TPB, 0, stream>>>(qkpart, attraw, GG);
      k_inter<48><<<BN_, TPB, 0, stream>>>(attraw, normq, normk, start, temperature, gi,
                                           qv_cache, cw_w, cw_b, gw, gb, attF);
      k_av<48><<<dim3(HWc / 128, BN_), TPB, 0, stream>>>(qkv, idx, attF, normq, normk, start,
                                                         out_all, sbuf);
    }
  }
  // qv_new
  k_qvnew<<<(CDIM * CDIM + TPB - 1) / TPB, TPB, 0, stream>>>(atts, qv_cache, out_qv);

  // gated channel-MLP (qkv dead from here)
  k_mgemm<bf16_t, bf16_t, 2><<<dim3(2, GX, BN_), TPB, 0, stream>>>(
      intra_gate_w, intra_gate_w, NOS, intra_gate_b, sbuf, sbuf, gated,
      CDIM, CDIM, CDIM, CDIM, CDIM);
  k_mgemm<bf16_t, float, 0><<<dim3(1, GX, BN_), TPB, 0, stream>>>(
      intra_down_w, intra_down_w, NOS, intra_down_b, gated, nullptr, dbuf,
      CDIM / 2, CDIM, CDIM, CDIM / 2, 0);
  k_mgemm<bf16_t, bf16_t, 1><<<dim3(2, GX, BN_), TPB, 0, stream>>>(
      intra_up_w, intra_up_w, NOS, intra_up_b, dbuf, out_all, out_all,
      CDIM, CDIM / 2, CDIM / 2, CDIM, CDIM);
  // x1 = x + proj(out_all)
  k_mgemm<float, float, 1><<<dim3(2, GX, BN_), TPB, 0, stream>>>(
      w_proj, w_proj, NOS, nullptr, out_all, x, x1, CDIM, CDIM, CDIM, CDIM, CDIM);
  // LN2
  k_ln<<<(BN_ * HWc + TPB - 1) / TPB, TPB, 0, stream>>>(x1, ln2_w, ln2_b, xn2);

  // FFN in 4 chunks of 85 channel-pairs; y1+y2 in ONE dispatch via dual-W (osplit=85)
  for (int ci = 0; ci < 4; ++ci) {
    int c0 = ci * 85;
    k_mgemm<bf16_t, float, 0><<<dim3(3, GX, BN_), TPB, 0, stream>>>(
        ffn_in_w + (size_t)c0 * CDIM, ffn_in_w + (size_t)(HID + c0) * CDIM, 85,
        nullptr, xn2, nullptr, y0c, 170, CDIM, CDIM, 170, 0);
    long totG = (long)BN_ * 85 * (HWc / 8);
    k_dwgeluv<<<(unsigned)((totG + TPB - 1) / TPB), TPB, 0, stream>>>(
        y0c, ffn_dw_w, zbuf, 85, c0, totG);
  }
  // out = x1 + c1x1(z, ffn_out_w)
  k_mgemm<float, float, 1><<<dim3(2, GX, BN_), TPB, 0, stream>>>(
      ffn_out_w, ffn_out_w, NOS, nullptr, zbuf, x1, out, CDIM, HID, HID, CDIM, CDIM);
}

// Round 9
// 927.315 us; speedup vs baseline: 1.1563x; 1.0818x over previous
//
#include <hip/hip_runtime.h>
#include <math.h>

#define TPB 256

constexpr int BN_  = 2;
constexpr int CDIM = 128;
constexpr int HH   = 192;
constexpr int WW   = 192;
constexpr int HWc  = HH * WW;      // 36864
constexpr int C3   = 384;
constexpr int HID  = 340;
constexpr int NL2  = 288;          // split-L chunks for QK^T
constexpr int CH2  = HWc / NL2;    // 128
constexpr int CV3  = 576;          // split-L chunks for cov
constexpr int CV3L = HWc / CV3;    // 64

typedef unsigned short bf16_t;
typedef __attribute__((ext_vector_type(8))) __bf16 bf16x8;
typedef __attribute__((ext_vector_type(4))) float f32x4;

__device__ __forceinline__ float b2f(bf16_t v) {
  unsigned u = ((unsigned)v) << 16;
  return __uint_as_float(u);
}
__device__ __forceinline__ bf16_t f2b(float f) {
  unsigned u = __float_as_uint(f);
  unsigned r = (u + 0x7FFFu + ((u >> 16) & 1u)) >> 16;
  return (bf16_t)r;
}
__device__ __forceinline__ float ldf(const float* p) { return *p; }
__device__ __forceinline__ float ldf(const bf16_t* p) { return b2f(*p); }
__device__ __forceinline__ void stf(float* p, float v) { *p = v; }
__device__ __forceinline__ void stf(bf16_t* p, float v) { *p = f2b(v); }

// vectorized 4-elem load/store (16B fp32 / 8B bf16)
__device__ __forceinline__ void ldv4(const float* p, float* v) {
  float4 t = *(const float4*)p;
  v[0] = t.x; v[1] = t.y; v[2] = t.z; v[3] = t.w;
}
__device__ __forceinline__ void ldv4(const bf16_t* p, float* v) {
  ushort4 t = *(const ushort4*)p;
  v[0] = b2f(t.x); v[1] = b2f(t.y); v[2] = b2f(t.z); v[3] = b2f(t.w);
}
__device__ __forceinline__ void stv4(float* p, const float* v) {
  float4 t; t.x = v[0]; t.y = v[1]; t.z = v[2]; t.w = v[3];
  *(float4*)p = t;
}
__device__ __forceinline__ void stv4(bf16_t* p, const float* v) {
  ushort4 t; t.x = f2b(v[0]); t.y = f2b(v[1]); t.z = f2b(v[2]); t.w = f2b(v[3]);
  *(ushort4*)p = t;
}

__device__ __forceinline__ float gelu_f(float x) {
  return 0.5f * x * (1.0f + erff(x * 0.7071067811865475f));
}

__device__ __forceinline__ void unpack8(uint4 v, float* rv) {
  unsigned wv[4] = {v.x, v.y, v.z, v.w};
#pragma unroll
  for (int j = 0; j < 8; ++j)
    rv[j + 1] = b2f((bf16_t)((wv[j >> 1] >> ((j & 1) * 16)) & 0xFFFFu));
}
__device__ __forceinline__ uint4 pack8(const float* a) {
  uint4 o;
  unsigned w[4];
#pragma unroll
  for (int p = 0; p < 4; ++p) {
    unsigned lo = f2b(a[2 * p]), hi = f2b(a[2 * p + 1]);
    w[p] = lo | (hi << 16);
  }
  o.x = w[0]; o.y = w[1]; o.z = w[2]; o.w = w[3];
  return o;
}

// ---------------- workspace layout (byte offsets) ----------------
constexpr size_t oATTRAW  = 0;
constexpr size_t oATTS    = 1327104;
constexpr size_t oNORMQ   = 1363968;
constexpr size_t oNORMK   = 1364992;
constexpr size_t oIDX     = 1366016;
constexpr size_t oMU      = 1366528;
constexpr size_t oCOV     = 1367040;
constexpr size_t oQKV     = 1572864;           // 56,623,104 B (bf16 2*384*36864)
constexpr size_t oXN      = 58195968;          // 18,874,368 B  xn / qk-partial / x1b
constexpr size_t oOUTALL  = 77070336;          // 18,874,368 B
constexpr size_t oSBUF    = 95944704;          // 18,874,368 B
constexpr size_t WS_NEED  = 114819072;
// aliases:
constexpr size_t oCHUNK1  = oOUTALL;
constexpr size_t oCOVPART = oOUTALL;           // 37,748,736 B (spans OUTALL+SBUF, both dead)
constexpr size_t oQKPART  = oXN;
constexpr size_t oGATED   = oQKV;
constexpr size_t oDBUF    = oQKV + 18874368;
constexpr size_t oY0C     = oOUTALL;           // 25,067,520 B (spans into oSBUF, both dead)
constexpr size_t oZ       = oQKV;
constexpr size_t oX1B     = oXN;               // bf16 x1 (xn/qkpart dead)

// ---------------- LayerNorm over channel dim (templated input) ----------------
template <typename TI>
__global__ __launch_bounds__(TPB) void k_ln(const TI* __restrict__ x,
                                            const float* __restrict__ w,
                                            const float* __restrict__ bias,
                                            bf16_t* __restrict__ out) {
  int t = blockIdx.x * TPB + threadIdx.x;
  if (t >= BN_ * HWc) return;
  int b = t / HWc, l = t - b * HWc;
  const TI* xb = x + (size_t)b * CDIM * HWc + l;
  float s = 0.f, s2 = 0.f;
#pragma unroll 4
  for (int c = 0; c < CDIM; ++c) { float v = ldf(&xb[(size_t)c * HWc]); s += v; s2 += v * v; }
  float mu  = s * (1.f / CDIM);
  float var = s2 * (1.f / CDIM) - mu * mu;
  float inv = 1.f / sqrtf(var + 1e-5f);
  bf16_t* ob = out + (size_t)b * CDIM * HWc + l;
#pragma unroll 4
  for (int c = 0; c < CDIM; ++c)
    stf(&ob[(size_t)c * HWc], (ldf(&xb[(size_t)c * HWc]) - mu) * inv * w[c] + bias[c]);
}

// ---------------- MFMA channel GEMM (256 thr, 64x128 tile, transposed-D epilogue) --
// out[b,o,l] = sum_c Wrow(o)[c] in[b,c,l];  Wrow(o) = o<osplit ? W+o*K : W2+(o-osplit)*K
// EPI: 0 = (+bias), 1 = (+bias)+aux, 2 = gelu(+bias)*aux
template <typename TO, typename TA, int EPI>
__global__ __launch_bounds__(TPB) void k_mgemm(const float* __restrict__ W,
                                               const float* __restrict__ W2, int osplit,
                                               const float* __restrict__ bias,
                                               const bf16_t* __restrict__ in,
                                               const TA* __restrict__ aux,
                                               TO* __restrict__ out, int O, int K,
                                               int ibr, int obr, int abr) {
  constexpr int L = HWc;
  constexpr int BM = 64, BN = 128, BK = 64, PK = 72;
  __shared__ bf16_t Wt[BM * PK];   // [o][k]
  __shared__ bf16_t At[BN * PK];   // [l][k]
  int b = blockIdx.z;
  const bf16_t* inb  = in  + (size_t)b * ibr * L;
  const TA*     auxb = aux ? aux + (size_t)b * abr * L : nullptr;
  TO*           outb = out + (size_t)b * obr * L;
  int o0 = blockIdx.x * BM, l0 = blockIdx.y * BN;
  int tid  = threadIdx.x;
  int lane = tid & 63, wid = tid >> 6;
  int wm = wid >> 1, wn = wid & 1;           // 2x2 wave grid, wave tile 32(O)x64(L)
  int cl = lane & 15, rg = lane >> 4;

  float wreg[4][4];
  uint4 areg[2][2];

  // ---- prologue: load k-tile 0 into registers ----
#pragma unroll
  for (int r = 0; r < 4; ++r) {
    int e = tid + r * 256;
    int o = e >> 4, k4 = (e & 15) * 4;
    int og = o0 + o;
#pragma unroll
    for (int j = 0; j < 4; ++j) wreg[r][j] = 0.f;
    if (og < O) {
      const float* wrow = (og < osplit) ? (W + (size_t)og * K)
                                        : (W2 + (size_t)(og - osplit) * K);
#pragma unroll
      for (int j = 0; j < 4; ++j)
        if (k4 + j < K) wreg[r][j] = wrow[k4 + j];
    }
  }
#pragma unroll
  for (int r = 0; r < 2; ++r) {
    int u = tid + r * 256;
    int k2 = u & 31, lb = u >> 5;
    int ka = k2 * 2;
    areg[r][0] = (uint4){0u, 0u, 0u, 0u};
    areg[r][1] = (uint4){0u, 0u, 0u, 0u};
    if (ka < K)     areg[r][0] = *(const uint4*)(&inb[(size_t)ka * L + l0 + lb * 8]);
    if (ka + 1 < K) areg[r][1] = *(const uint4*)(&inb[(size_t)(ka + 1) * L + l0 + lb * 8]);
  }

  f32x4 acc[2][4];
#pragma unroll
  for (int m = 0; m < 2; ++m)
#pragma unroll
    for (int n = 0; n < 4; ++n) acc[m][n] = (f32x4){0.f, 0.f, 0.f, 0.f};

  for (int k0 = 0; k0 < K; k0 += BK) {
    // ---- regs -> LDS ----
#pragma unroll
    for (int r = 0; r < 4; ++r) {
      int e = tid + r * 256;
      int o = e >> 4, k4 = (e & 15) * 4;
      ushort4 pk;
      pk.x = f2b(wreg[r][0]); pk.y = f2b(wreg[r][1]);
      pk.z = f2b(wreg[r][2]); pk.w = f2b(wreg[r][3]);
      *(ushort4*)(&Wt[o * PK + k4]) = pk;
    }
#pragma unroll
    for (int r = 0; r < 2; ++r) {
      int u = tid + r * 256;
      int k2 = u & 31, lb = u >> 5;
      unsigned wa[4] = {areg[r][0].x, areg[r][0].y, areg[r][0].z, areg[r][0].w};
      unsigned wb[4] = {areg[r][1].x, areg[r][1].y, areg[r][1].z, areg[r][1].w};
#pragma unroll
      for (int j = 0; j < 8; ++j) {
        unsigned va = (wa[j >> 1] >> ((j & 1) * 16)) & 0xFFFFu;
        unsigned vb = (wb[j >> 1] >> ((j & 1) * 16)) & 0xFFFFu;
        *(unsigned*)(&At[(lb * 8 + j) * PK + k2 * 2]) = va | (vb << 16);
      }
    }
    __syncthreads();
    // ---- issue next k-tile loads (overlap with MFMA below) ----
    int kn = k0 + BK;
    if (kn < K) {
#pragma unroll
      for (int r = 0; r < 4; ++r) {
        int e = tid + r * 256;
        int o = e >> 4, k4 = (e & 15) * 4;
        int og = o0 + o;
#pragma unroll
        for (int j = 0; j < 4; ++j) wreg[r][j] = 0.f;
        if (og < O) {
          const float* wrow = (og < osplit) ? (W + (size_t)og * K)
                                            : (W2 + (size_t)(og - osplit) * K);
#pragma unroll
          for (int j = 0; j < 4; ++j)
            if (kn + k4 + j < K) wreg[r][j] = wrow[kn + k4 + j];
        }
      }
#pragma unroll
      for (int r = 0; r < 2; ++r) {
        int u = tid + r * 256;
        int k2 = u & 31, lb = u >> 5;
        int ka = kn + k2 * 2;
        areg[r][0] = (uint4){0u, 0u, 0u, 0u};
        areg[r][1] = (uint4){0u, 0u, 0u, 0u};
        if (ka < K)     areg[r][0] = *(const uint4*)(&inb[(size_t)ka * L + l0 + lb * 8]);
        if (ka + 1 < K) areg[r][1] = *(const uint4*)(&inb[(size_t)(ka + 1) * L + l0 + lb * 8]);
      }
    }
    // ---- MFMA: A = act fragment (rows = l), B = W fragment (cols = o) => D[l][o]
#pragma unroll
    for (int kk = 0; kk < 2; ++kk) {
      int kof = kk * 32 + rg * 8;
      bf16x8 a[2], bfr[4];
#pragma unroll
      for (int m = 0; m < 2; ++m)
        a[m] = *(const bf16x8*)(&Wt[(wm * 32 + m * 16 + cl) * PK + kof]);
#pragma unroll
      for (int n = 0; n < 4; ++n)
        bfr[n] = *(const bf16x8*)(&At[(wn * 64 + n * 16 + cl) * PK + kof]);
#pragma unroll
      for (int m = 0; m < 2; ++m)
#pragma unroll
        for (int n = 0; n < 4; ++n)
          acc[m][n] = __builtin_amdgcn_mfma_f32_16x16x32_bf16(bfr[n], a[m], acc[m][n], 0, 0, 0);
    }
    __syncthreads();
  }
  // ---- epilogue: D[l][o] — thread holds 4 consecutive l at fixed o => vector I/O ----
#pragma unroll
  for (int m = 0; m < 2; ++m) {
    int og = o0 + wm * 32 + m * 16 + cl;
    if (og >= O) continue;
    float bv = bias ? bias[og] : 0.f;
#pragma unroll
    for (int n = 0; n < 4; ++n) {
      int lcol = l0 + wn * 64 + n * 16 + rg * 4;
      size_t off = (size_t)og * L + lcol;
      float v[4];
#pragma unroll
      for (int r = 0; r < 4; ++r) v[r] = acc[m][n][r] + bv;
      if (EPI == 1) {
        float a4[4]; ldv4(&auxb[off], a4);
#pragma unroll
        for (int r = 0; r < 4; ++r) v[r] += a4[r];
      } else if (EPI == 2) {
        float a4[4]; ldv4(&auxb[off], a4);
#pragma unroll
        for (int r = 0; r < 4; ++r) v[r] = gelu_f(v[r]) * a4[r];
      }
      stv4(&outb[off], v);
    }
  }
}

// ---------------- depthwise 3x3 SAME, vectorized 8 px/thread ----------------
__global__ __launch_bounds__(TPB) void k_dw3v(const bf16_t* __restrict__ in,
                                              const float* __restrict__ wt,
                                              bf16_t* __restrict__ out,
                                              int Cc, int c0, int CoutTotal, long totalG) {
  long t = (long)blockIdx.x * TPB + threadIdx.x;
  if (t >= totalG) return;
  int g = (int)(t % (HWc / 8));
  long bc = t / (HWc / 8);
  int cl = (int)(bc % Cc);
  int b = (int)(bc / Cc);
  int h = g / (WW / 8), w8 = (g % (WW / 8)) * 8;
  const bf16_t* ib = in + ((size_t)b * Cc + cl) * HWc;
  const float* wc = wt + (size_t)(c0 + cl) * 9;
  float rowv[3][10];
#pragma unroll
  for (int dy = -1; dy <= 1; ++dy) {
    float* rv = rowv[dy + 1];
    int hh = h + dy;
    if ((unsigned)hh >= (unsigned)HH) {
#pragma unroll
      for (int j = 0; j < 10; ++j) rv[j] = 0.f;
      continue;
    }
    const bf16_t* rp = ib + hh * WW + w8;
    unpack8(*(const uint4*)rp, rv);
    rv[0] = (w8 > 0) ? b2f(rp[-1]) : 0.f;
    rv[9] = (w8 + 8 < WW) ? b2f(rp[8]) : 0.f;
  }
  float a[8];
#pragma unroll
  for (int j = 0; j < 8; ++j) {
    float s = 0.f;
#pragma unroll
    for (int dy = 0; dy < 3; ++dy)
#pragma unroll
      for (int dx = 0; dx < 3; ++dx)
        s += rowv[dy][j + dx] * wc[dy * 3 + dx];
    a[j] = s;
  }
  *(uint4*)(&out[((size_t)b * CoutTotal + c0 + cl) * HWc + h * WW + w8]) = pack8(a);
}

// ---------------- mu over cf = 0.5*(q_b0+q_b1) ----------------
__global__ __launch_bounds__(TPB) void k_mu(const bf16_t* __restrict__ qkv, float* __restrict__ mu) {
  int c = blockIdx.x;
  __shared__ float red[TPB];
  float s = 0.f;
  for (int l = threadIdx.x; l < HWc; l += TPB)
    s += 0.5f * (b2f(qkv[(size_t)c * HWc + l]) + b2f(qkv[(size_t)C3 * HWc + (size_t)c * HWc + l]));
  red[threadIdx.x] = s;
  __syncthreads();
  for (int st = TPB / 2; st > 0; st >>= 1) {
    if (threadIdx.x < st) red[threadIdx.x] += red[threadIdx.x + st];
    __syncthreads();
  }
  if (threadIdx.x == 0) mu[c] = red[0] / HWc;
}

// ---------------- split-L cov partials (576 chunks x 64 cols, conflict-free) --------
__global__ __launch_bounds__(TPB) void k_cov3(const bf16_t* __restrict__ qkv,
                                              float* __restrict__ part) {
  int chunk = blockIdx.x;
  int tid = threadIdx.x, ti = tid & 15, tj = tid >> 4;
  __shared__ float xs[CDIM][65];
  int base = chunk * CV3L;
#pragma unroll
  for (int r4 = 0; r4 < 4; ++r4) {
    int u = tid + r4 * 256;
    int r = u >> 3, c8 = (u & 7) * 8;
    uint4 vq = *(const uint4*)(&qkv[(size_t)r * HWc + base + c8]);
    uint4 vk = *(const uint4*)(&qkv[(size_t)C3 * HWc + (size_t)r * HWc + base + c8]);
    unsigned wq[4] = {vq.x, vq.y, vq.z, vq.w};
    unsigned wk[4] = {vk.x, vk.y, vk.z, vk.w};
#pragma unroll
    for (int j = 0; j < 8; ++j) {
      float q = b2f((bf16_t)((wq[j >> 1] >> ((j & 1) * 16)) & 0xFFFFu));
      float k = b2f((bf16_t)((wk[j >> 1] >> ((j & 1) * 16)) & 0xFFFFu));
      xs[r][c8 + j] = 0.5f * (q + k);
    }
  }
  __syncthreads();
  float acc[8][8];
#pragma unroll
  for (int m = 0; m < 8; ++m)
#pragma unroll
    for (int n = 0; n < 8; ++n) acc[m][n] = 0.f;
#pragma unroll 2
  for (int l = 0; l < CV3L; ++l) {
    float a[8], b[8];
#pragma unroll
    for (int m = 0; m < 8; ++m) a[m] = xs[ti + 16 * m][l];
#pragma unroll
    for (int n = 0; n < 8; ++n) b[n] = xs[tj + 16 * n][l];
#pragma unroll
    for (int m = 0; m < 8; ++m)
#pragma unroll
      for (int n = 0; n < 8; ++n) acc[m][n] += a[m] * b[n];
  }
  float* pb = part + (size_t)chunk * CDIM * CDIM;
#pragma unroll
  for (int m = 0; m < 8; ++m)
#pragma unroll
    for (int n = 0; n < 8; ++n)
      pb[(ti + 16 * m) * CDIM + tj + 16 * n] = acc[m][n];
}

// ---------------- reduce cov partials + mean correction ----------------
__global__ __launch_bounds__(TPB) void k_covred(const float* __restrict__ part,
                                                const float* __restrict__ mu,
                                                float* __restrict__ cov) {
  int t = blockIdx.x * TPB + threadIdx.x;
  if (t >= CDIM * CDIM) return;
  float s = 0.f;
  for (int p = 0; p < CV3; ++p) s += part[(size_t)p * CDIM * CDIM + t];
  int c = t >> 7, d = t & 127;
  cov[t] = s - (float)HWc * mu[c] * mu[d];
}

// ---------------- parallel stable rank ----------------
__global__ __launch_bounds__(CDIM) void k_rank(const float* __restrict__ cov,
                                               int* __restrict__ idx) {
  __shared__ float dsd[CDIM], score[CDIM];
  int tid = threadIdx.x;
  dsd[tid] = sqrtf(cov[tid * CDIM + tid]);
  __syncthreads();
  {
    float s = 0.f, di = dsd[tid];
    for (int d = 0; d < CDIM; ++d) s += cov[tid * CDIM + d] / (di * dsd[d]);
    score[tid] = s;
  }
  __syncthreads();
  {
    float my = score[tid];
    int rank = 0;
    for (int d = 0; d < CDIM; ++d)
      rank += (score[d] > my) || (score[d] == my && d < tid);
    idx[rank] = tid;
  }
}

// ---------------- row norms of permuted q,k ----------------
__global__ __launch_bounds__(TPB) void k_norms(const bf16_t* __restrict__ qkv,
                                               const int* __restrict__ idx,
                                               float* __restrict__ normq,
                                               float* __restrict__ normk) {
  int p = blockIdx.x, b = blockIdx.y, which = blockIdx.z;
  int ch = idx[p] + which * CDIM;
  const bf16_t* row = qkv + ((size_t)b * C3 + ch) * HWc;
  __shared__ float red[TPB];
  float s = 0.f;
  for (int l = threadIdx.x; l < HWc; l += TPB) { float v = b2f(row[l]); s += v * v; }
  red[threadIdx.x] = s;
  __syncthreads();
  for (int st = TPB / 2; st > 0; st >>= 1) {
    if (threadIdx.x < st) red[threadIdx.x] += red[threadIdx.x + st];
    __syncthreads();
  }
  if (threadIdx.x == 0) {
    float n = fmaxf(sqrtf(red[0]), 1e-12f);
    (which ? normk : normq)[b * CDIM + p] = n;
  }
}

// ---------------- QK^T split-L partials ----------------
template <int G>
__global__ __launch_bounds__(TPB) void k_qk2(const bf16_t* __restrict__ qkv,
                                             const int* __restrict__ idx, int start,
                                             float* __restrict__ partial) {
  constexpr int RT = G / 16;
  constexpr int U  = G * CH2 / 8;
  int nl = blockIdx.x, b = blockIdx.y;
  __shared__ float qs[G][CH2 + 2], ks[G][CH2 + 2];
  __shared__ int idxg[G];
  int tid = threadIdx.x;
  if (tid < G) idxg[tid] = idx[start + tid];
  __syncthreads();
  int l0 = nl * CH2;
  for (int u = tid; u < U; u += TPB) {
    int r = u / (CH2 / 8), c8 = (u % (CH2 / 8)) * 8;
    int ch = idxg[r];
    uint4 vq = *(const uint4*)(&qkv[((size_t)b * C3 + ch) * HWc + l0 + c8]);
    uint4 vk = *(const uint4*)(&qkv[((size_t)b * C3 + CDIM + ch) * HWc + l0 + c8]);
    unsigned wq[4] = {vq.x, vq.y, vq.z, vq.w};
    unsigned wk[4] = {vk.x, vk.y, vk.z, vk.w};
#pragma unroll
    for (int j = 0; j < 8; ++j) {
      qs[r][c8 + j] = b2f((bf16_t)((wq[j >> 1] >> ((j & 1) * 16)) & 0xFFFFu));
      ks[r][c8 + j] = b2f((bf16_t)((wk[j >> 1] >> ((j & 1) * 16)) & 0xFFFFu));
    }
  }
  __syncthreads();
  int ti = tid & 15, tj = tid >> 4;
  float acc[RT][RT];
#pragma unroll
  for (int m = 0; m < RT; ++m)
#pragma unroll
    for (int n = 0; n < RT; ++n) acc[m][n] = 0.f;
#pragma unroll 4
  for (int l = 0; l < CH2; ++l) {
    float qa[RT], kb[RT];
#pragma unroll
    for (int m = 0; m < RT; ++m) qa[m] = qs[ti * RT + m][l];
#pragma unroll
    for (int n = 0; n < RT; ++n) kb[n] = ks[tj * RT + n][l];
#pragma unroll
    for (int m = 0; m < RT; ++m)
#pragma unroll
      for (int n = 0; n < RT; ++n) acc[m][n] += qa[m] * kb[n];
  }
  float* pb = partial + ((size_t)(b * NL2) + nl) * G * G;
#pragma unroll
  for (int m = 0; m < RT; ++m)
#pragma unroll
    for (int n = 0; n < RT; ++n)
      pb[(ti * RT + m) * G + tj * RT + n] = acc[m][n];
}

// ---------------- reduce QK^T partials over chunks ----------------
__global__ __launch_bounds__(TPB) void k_qkred(const float* __restrict__ partial,
                                               float* __restrict__ attraw, int GG) {
  int t = blockIdx.x * TPB + threadIdx.x;
  if (t >= BN_ * GG) return;
  int b = t / GG, e = t - b * GG;
  const float* pb = partial + (size_t)b * NL2 * GG + e;
  float s = 0.f;
  for (int nl = 0; nl < NL2; ++nl) s += pb[(size_t)nl * GG];
  attraw[t] = s;
}

// ---------------- per-group softmax + pooled-cache MLP ----------------
template <int G>
__global__ __launch_bounds__(TPB) void k_inter(const float* __restrict__ attraw,
                                               const float* __restrict__ normq,
                                               const float* __restrict__ normk, int start,
                                               const float* __restrict__ temperature, int gi,
                                               const float* __restrict__ qv_cache,
                                               const float* __restrict__ cw_w,
                                               const float* __restrict__ cw_b,
                                               const float* __restrict__ g_w,
                                               const float* __restrict__ g_b,
                                               float* __restrict__ attF) {
  constexpr int GG = G * G;
  int b = blockIdx.x;
  __shared__ float att[GG], t1[GG], sc[GG], sh[GG], x1p[GG], t2[GG];
  int tid = threadIdx.x;
  float temp = temperature[gi];
  for (int e = tid; e < GG; e += TPB) {
    int i = e / G, j = e % G;
    att[e] = attraw[b * GG + e] * temp /
             (normq[b * CDIM + start + i] * normk[b * CDIM + start + j]);
  }
  __syncthreads();
  if (tid < G) {
    float mx = -3.4e38f;
    for (int j = 0; j < G; ++j) mx = fmaxf(mx, att[tid * G + j]);
    float ssum = 0.f;
    for (int j = 0; j < G; ++j) { float ex = expf(att[tid * G + j] - mx); att[tid * G + j] = ex; ssum += ex; }
    float inv = 1.f / ssum;
    for (int j = 0; j < G; ++j) att[tid * G + j] *= inv;
  }
  __syncthreads();
  for (int e = tid; e < GG; e += TPB) {
    int o = e / G, p = e % G;
    int so = o * CDIM / G, eo = ((o + 1) * CDIM + G - 1) / G;
    int sp = p * CDIM / G, ep = ((p + 1) * CDIM + G - 1) / G;
    float ssum = 0.f;
    for (int i2 = so; i2 < eo; ++i2)
      for (int j2 = sp; j2 < ep; ++j2) ssum += qv_cache[i2 * CDIM + j2];
    t1[e] = ssum / (float)((eo - so) * (ep - sp)) + att[e];
  }
  __syncthreads();
  for (int e = tid; e < 2 * GG; e += TPB) {
    int o = e / G, p = e % G;
    float v = cw_b[o];
    for (int c = 0; c < G; ++c) v += cw_w[o * G + c] * t1[c * G + p];
    if (o < G) sc[o * G + p] = v; else sh[(o - G) * G + p] = v;
  }
  __syncthreads();
  for (int e = tid; e < GG; e += TPB) x1p[e] = att[e] * sc[e] + sh[e];
  __syncthreads();
  for (int e = tid; e < GG; e += TPB) {
    int o = e / G, p = e % G;
    float v = g_b[o];
    for (int c = 0; c < G; ++c) v += g_w[o * G + c] * x1p[c * G + p];
    t2[e] = v;
  }
  __syncthreads();
  for (int e = tid; e < GG; e += TPB)
    attF[(size_t)b * GG + e] = x1p[e] * gelu_f(t2[e]) + att[e];
}

// ---------------- att @ V + (qn+kn) fused ----------------
template <int G>
__global__ __launch_bounds__(TPB) void k_av(const bf16_t* __restrict__ qkv,
                                            const int* __restrict__ idx,
                                            const float* __restrict__ attF,
                                            const float* __restrict__ normq,
                                            const float* __restrict__ normk, int start,
                                            bf16_t* __restrict__ out_all,
                                            bf16_t* __restrict__ s_buf) {
  constexpr int GH = G / 2;
  int b = blockIdx.y;
  int l0 = blockIdx.x * 128;
  __shared__ float vt[G][129];
  __shared__ float attL[G * G];
  __shared__ int idxg[G];
  int tid = threadIdx.x;
  if (tid < G) idxg[tid] = idx[start + tid];
  for (int e = tid; e < G * G; e += TPB) attL[e] = attF[(size_t)b * G * G + e];
  __syncthreads();
  for (int e = tid; e < G * 128; e += TPB) {
    int j = e >> 7, c = e & 127;
    vt[j][c] = b2f(qkv[((size_t)b * C3 + 2 * CDIM + idxg[j]) * HWc + l0 + c]);
  }
  __syncthreads();
  int ll = tid & 127, half = tid >> 7;
  float acc[GH];
#pragma unroll
  for (int i = 0; i < GH; ++i) acc[i] = 0.f;
  for (int j = 0; j < G; ++j) {
    float vv = vt[j][ll];
#pragma unroll
    for (int i = 0; i < GH; ++i) acc[i] += attL[(half * GH + i) * G + j] * vv;
  }
#pragma unroll
  for (int i = 0; i < GH; ++i) {
    int ig = half * GH + i;
    int p = start + ig;
    int ch = idxg[ig];
    float qv = b2f(qkv[((size_t)b * C3 + ch) * HWc + l0 + ll]);
    float kv = b2f(qkv[((size_t)b * C3 + CDIM + ch) * HWc + l0 + ll]);
    float tmp = qv / normq[b * CDIM + p] + kv / normk[b * CDIM + p];
    size_t off = ((size_t)b * CDIM + p) * HWc + l0 + ll;
    stf(&out_all[off], acc[i]);
    stf(&s_buf[off], acc[i] + tmp);
  }
}

// ---------------- qv_new: bilinear upsample + floor + EMA ----------------
__global__ __launch_bounds__(TPB) void k_qvnew(const float* __restrict__ attsF,
                                               const float* __restrict__ qv_cache,
                                               float* __restrict__ out_qv) {
  int t = blockIdx.x * TPB + threadIdx.x;
  if (t >= CDIM * CDIM) return;
  int r = t >> 7, cq = t & 127;
  const int gs[4]   = {16, 32, 32, 48};
  const int base[4] = {0, 512, 2560, 4608};
  float acc = 0.f;
  for (int gi = 0; gi < 4; ++gi) {
    int g = gs[gi], gg = g * g;
    const float* a0 = attsF + base[gi];
    float scale = (float)g / CDIM;
    float fr = (r + 0.5f) * scale - 0.5f;
    float fc = (cq + 0.5f) * scale - 0.5f;
    float flr = floorf(fr), flc = floorf(fc);
    int i0 = (int)flr, j0 = (int)flc;
    float wr = fr - flr, wcw = fc - flc;
    int i0c = max(i0, 0), i1c = min(i0 + 1, g - 1);
    int j0c = max(j0, 0), j1c = min(j0 + 1, g - 1);
    float m00 = 0.5f * (a0[i0c * g + j0c] + a0[gg + i0c * g + j0c]);
    float m01 = 0.5f * (a0[i0c * g + j1c] + a0[gg + i0c * g + j1c]);
    float m10 = 0.5f * (a0[i1c * g + j0c] + a0[gg + i1c * g + j0c]);
    float m11 = 0.5f * (a0[i1c * g + j1c] + a0[gg + i1c * g + j1c]);
    float val = (1.f - wr) * ((1.f - wcw) * m00 + wcw * m01)
              + wr * ((1.f - wcw) * m10 + wcw * m11);
    acc += floorf(val);
  }
  out_qv[t] = qv_cache[t] * 0.9f + acc * 0.1f;
}

// ---------------- ffn: dw3 pair + gelu-gate, vectorized 8 px/thread ----------------
__global__ __launch_bounds__(TPB) void k_dwgeluv(const bf16_t* __restrict__ y0c,
                                                 const float* __restrict__ wt,
                                                 bf16_t* __restrict__ z,
                                                 int Cc, int c0, long totalG) {
  long t = (long)blockIdx.x * TPB + threadIdx.x;
  if (t >= totalG) return;
  int g = (int)(t % (HWc / 8));
  long bc = t / (HWc / 8);
  int cl = (int)(bc % Cc);
  int b = (int)(bc / Cc);
  int h = g / (WW / 8), w8 = (g % (WW / 8)) * 8;
  const bf16_t* i1 = y0c + ((size_t)b * 2 * Cc + cl) * HWc;
  const bf16_t* i2 = y0c + ((size_t)b * 2 * Cc + Cc + cl) * HWc;
  const float* w1 = wt + (size_t)(c0 + cl) * 9;
  const float* w2 = wt + (size_t)(HID + c0 + cl) * 9;
  float r1[3][10], r2[3][10];
#pragma unroll
  for (int dy = -1; dy <= 1; ++dy) {
    float* v1 = r1[dy + 1];
    float* v2 = r2[dy + 1];
    int hh = h + dy;
    if ((unsigned)hh >= (unsigned)HH) {
#pragma unroll
      for (int j = 0; j < 10; ++j) { v1[j] = 0.f; v2[j] = 0.f; }
      continue;
    }
    const bf16_t* p1 = i1 + hh * WW + w8;
    const bf16_t* p2 = i2 + hh * WW + w8;
    unpack8(*(const uint4*)p1, v1);
    unpack8(*(const uint4*)p2, v2);
    bool hasL = (w8 > 0), hasR = (w8 + 8 < WW);
    v1[0] = hasL ? b2f(p1[-1]) : 0.f;
    v1[9] = hasR ? b2f(p1[8]) : 0.f;
    v2[0] = hasL ? b2f(p2[-1]) : 0.f;
    v2[9] = hasR ? b2f(p2[8]) : 0.f;
  }
  float o[8];
#pragma unroll
  for (int j = 0; j < 8; ++j) {
    float a1 = 0.f, a2 = 0.f;
#pragma unroll
    for (int dy = 0; dy < 3; ++dy)
#pragma unroll
      for (int dx = 0; dx < 3; ++dx) {
        a1 += r1[dy][j + dx] * w1[dy * 3 + dx];
        a2 += r2[dy][j + dx] * w2[dy * 3 + dx];
      }
    o[j] = gelu_f(a1) * a2;
  }
  *(uint4*)(&z[((size_t)b * HID + c0 + cl) * HWc + h * WW + w8]) = pack8(o);
}

// ---------------- host ----------------
extern "C" void kernel_launch(void* const* d_in, const int* in_sizes, int n_in,
                              void* d_out, int out_size, void* d_ws, size_t ws_size,
                              hipStream_t stream) {
  if (ws_size < WS_NEED) return;  // workspace insufficient

  const float* x        = (const float*)d_in[0];
  const float* qv_cache = (const float*)d_in[1];
  const float* ln1_w    = (const float*)d_in[2];
  const float* ln1_b    = (const float*)d_in[3];
  const float* ln2_w    = (const float*)d_in[4];
  const float* ln2_b    = (const float*)d_in[5];
  const float* temperature = (const float*)d_in[6];
  const float* w_qkv    = (const float*)d_in[7];
  const float* w_qkv_dw = (const float*)d_in[8];
  const float* w_proj   = (const float*)d_in[9];
  const float* intra_down_w = (const float*)d_in[10];
  const float* intra_down_b = (const float*)d_in[11];
  const float* intra_up_w   = (const float*)d_in[12];
  const float* intra_up_b   = (const float*)d_in[13];
  const float* intra_gate_w = (const float*)d_in[14];
  const float* intra_gate_b = (const float*)d_in[15];
  const float* ffn_in_w  = (const float*)d_in[32];
  const float* ffn_dw_w  = (const float*)d_in[33];
  const float* ffn_out_w = (const float*)d_in[34];

  char* wsb = (char*)d_ws;
  float* out    = (float*)d_out;
  float* out_qv = out + (size_t)BN_ * CDIM * HWc;
  bf16_t* xn2   = (bf16_t*)d_out;   // scratch in d_out's out-region (dead before final write)

  float*  attraw  = (float*)(wsb + oATTRAW);
  float*  atts    = (float*)(wsb + oATTS);
  float*  normq   = (float*)(wsb + oNORMQ);
  float*  normk   = (float*)(wsb + oNORMK);
  int*    idx     = (int*)(wsb + oIDX);
  float*  mu      = (float*)(wsb + oMU);
  float*  cov     = (float*)(wsb + oCOV);
  bf16_t* qkv     = (bf16_t*)(wsb + oQKV);
  bf16_t* xn      = (bf16_t*)(wsb + oXN);
  bf16_t* out_all = (bf16_t*)(wsb + oOUTALL);
  bf16_t* sbuf    = (bf16_t*)(wsb + oSBUF);
  bf16_t* chunk1  = (bf16_t*)(wsb + oCHUNK1);
  float*  covpart = (float*)(wsb + oCOVPART);
  float*  qkpart  = (float*)(wsb + oQKPART);
  bf16_t* gated   = (bf16_t*)(wsb + oGATED);
  bf16_t* dbuf    = (bf16_t*)(wsb + oDBUF);
  bf16_t* x1b     = (bf16_t*)(wsb + oX1B);
  bf16_t* y0c     = (bf16_t*)(wsb + oY0C);
  bf16_t* zbuf    = (bf16_t*)(wsb + oZ);

  const int GX = HWc / 128;  // 288 l-tiles
  const int NOS = 1 << 30;   // "no osplit"

  // 1. LN1: xn = LN(x)
  k_ln<float><<<(BN_ * HWc + TPB - 1) / TPB, TPB, 0, stream>>>(x, ln1_w, ln1_b, xn);

  // 2+3. qkv = dw3(c1x1(xn, w_qkv)) in 3 chunks of 128 channels
  for (int ci = 0; ci < 3; ++ci) {
    int c0 = ci * 128;
    k_mgemm<bf16_t, float, 0><<<dim3(2, GX, BN_), TPB, 0, stream>>>(
        w_qkv + (size_t)c0 * CDIM, w_qkv, NOS, nullptr, xn, nullptr, chunk1,
        128, CDIM, CDIM, 128, 0);
    long totG = (long)BN_ * 128 * (HWc / 8);
    k_dw3v<<<(unsigned)((totG + TPB - 1) / TPB), TPB, 0, stream>>>(
        chunk1, w_qkv_dw, qkv, 128, c0, C3, totG);
  }

  // 4-7. correlation sort
  k_mu<<<CDIM, TPB, 0, stream>>>(qkv, mu);
  k_cov3<<<CV3, TPB, 0, stream>>>(qkv, covpart);
  k_covred<<<(CDIM * CDIM + TPB - 1) / TPB, TPB, 0, stream>>>(covpart, mu, cov);
  k_rank<<<1, CDIM, 0, stream>>>(cov, idx);
  // 8. norms
  k_norms<<<dim3(CDIM, BN_, 2), TPB, 0, stream>>>(qkv, idx, normq, normk);

  // groups (xn dead from here -> qkpart overlays it)
  const int gsz[4]    = {16, 32, 32, 48};
  const int gstart[4] = {0, 16, 48, 80};
  const int abase[4]  = {0, 512, 2560, 4608};
  for (int gi = 0; gi < 4; ++gi) {
    int start = gstart[gi];
    const float* cw_w = (const float*)d_in[16 + 4 * gi];
    const float* cw_b = (const float*)d_in[17 + 4 * gi];
    const float* gw   = (const float*)d_in[18 + 4 * gi];
    const float* gb   = (const float*)d_in[19 + 4 * gi];
    float* attF = atts + abase[gi];
    int GG = gsz[gi] * gsz[gi];
    if (gsz[gi] == 16) {
      k_qk2<16><<<dim3(NL2, BN_), TPB, 0, stream>>>(qkv, idx, start, qkpart);
      k_qkred<<<(BN_ * GG + TPB - 1) / TPB, TPB, 0, stream>>>(qkpart, attraw, GG);
      k_inter<16><<<BN_, TPB, 0, stream>>>(attraw, normq, normk, start, temperature, gi,
                                           qv_cache, cw_w, cw_b, gw, gb, attF);
      k_av<16><<<dim3(HWc / 128, BN_), TPB, 0, stream>>>(qkv, idx, attF, normq, normk, start,
                                                         out_all, sbuf);
    } else if (gsz[gi] == 32) {
      k_qk2<32><<<dim3(NL2, BN_), TPB, 0, stream>>>(qkv, idx, start, qkpart);
      k_qkred<<<(BN_ * GG + TPB - 1) / TPB, TPB, 0, stream>>>(qkpart, attraw, GG);
      k_inter<32><<<BN_, TPB, 0, stream>>>(attraw, normq, normk, start, temperature, gi,
                                           qv_cache, cw_w, cw_b, gw, gb, attF);
      k_av<32><<<dim3(HWc / 128, BN_), TPB, 0, stream>>>(qkv, idx, attF, normq, normk, start,
                                                         out_all, sbuf);
    } else {
      k_qk2<48><<<dim3(NL2, BN_), TPB, 0, stream>>>(qkv, idx, start, qkpart);
      k_qkred<<<(BN_ * GG + TPB - 1) / TPB, TPB, 0, stream>>>(qkpart, attraw, GG);
      k_inter<48><<<BN_, TPB, 0, stream>>>(attraw, normq, normk, start, temperature, gi,
                                           qv_cache, cw_w, cw_b, gw, gb, attF);
      k_av<48><<<dim3(HWc / 128, BN_), TPB, 0, stream>>>(qkv, idx, attF, normq, normk, start,
                                                         out_all, sbuf);
    }
  }
  // qv_new
  k_qvnew<<<(CDIM * CDIM + TPB - 1) / TPB, TPB, 0, stream>>>(atts, qv_cache, out_qv);

  // gated channel-MLP (qkv dead from here)
  k_mgemm<bf16_t, bf16_t, 2><<<dim3(2, GX, BN_), TPB, 0, stream>>>(
      intra_gate_w, intra_gate_w, NOS, intra_gate_b, sbuf, sbuf, gated,
      CDIM, CDIM, CDIM, CDIM, CDIM);
  k_mgemm<bf16_t, float, 0><<<dim3(1, GX, BN_), TPB, 0, stream>>>(
      intra_down_w, intra_down_w, NOS, intra_down_b, gated, nullptr, dbuf,
      CDIM / 2, CDIM, CDIM, CDIM / 2, 0);
  k_mgemm<bf16_t, bf16_t, 1><<<dim3(2, GX, BN_), TPB, 0, stream>>>(
      intra_up_w, intra_up_w, NOS, intra_up_b, dbuf, out_all, out_all,
      CDIM, CDIM / 2, CDIM / 2, CDIM, CDIM);
  // x1b = bf16(x + proj(out_all))   (x1b overlays dead xn/qkpart region)
  k_mgemm<bf16_t, float, 1><<<dim3(2, GX, BN_), TPB, 0, stream>>>(
      w_proj, w_proj, NOS, nullptr, out_all, x, x1b, CDIM, CDIM, CDIM, CDIM, CDIM);
  // LN2: xn2 = LN(x1b)  (xn2 lives in d_out's out-region until final write)
  k_ln<bf16_t><<<(BN_ * HWc + TPB - 1) / TPB, TPB, 0, stream>>>(x1b, ln2_w, ln2_b, xn2);

  // FFN in 4 chunks of 85 channel-pairs; y1+y2 in ONE dispatch via dual-W (osplit=85)
  for (int ci = 0; ci < 4; ++ci) {
    int c0 = ci * 85;
    k_mgemm<bf16_t, float, 0><<<dim3(3, GX, BN_), TPB, 0, stream>>>(
        ffn_in_w + (size_t)c0 * CDIM, ffn_in_w + (size_t)(HID + c0) * CDIM, 85,
        nullptr, xn2, nullptr, y0c, 170, CDIM, CDIM, 170, 0);
    long totG = (long)BN_ * 85 * (HWc / 8);
    k_dwgeluv<<<(unsigned)((totG + TPB - 1) / TPB), TPB, 0, stream>>>(
        y0c, ffn_dw_w, zbuf, 85, c0, totG);
  }
  // out = x1b + c1x1(z, ffn_out_w)  (xn2 dead; out written fp32 over d_out)
  k_mgemm<float, bf16_t, 1><<<dim3(2, GX, BN_), TPB, 0, stream>>>(
      ffn_out_w, ffn_out_w, NOS, nullptr, zbuf, x1b, out, CDIM, HID, HID, CDIM, CDIM);
}

// Round 10
// 869.606 us; speedup vs baseline: 1.2330x; 1.0664x over previous
//
#include <hip/hip_runtime.h>
#include <math.h>

#define TPB 256

constexpr int BN_  = 2;
constexpr int CDIM = 128;
constexpr int HH   = 192;
constexpr int WW   = 192;
constexpr int HWc  = HH * WW;      // 36864
constexpr int C3   = 384;
constexpr int HID  = 340;
constexpr int NL2  = 288;          // split-L chunks for QK^T
constexpr int CH2  = HWc / NL2;    // 128
constexpr int CV3  = 576;          // split-L chunks for cov
constexpr int CV3L = HWc / CV3;    // 64

typedef unsigned short bf16_t;
typedef __attribute__((ext_vector_type(8))) __bf16 bf16x8;
typedef __attribute__((ext_vector_type(4))) float f32x4;

__device__ __forceinline__ float b2f(bf16_t v) {
  unsigned u = ((unsigned)v) << 16;
  return __uint_as_float(u);
}
__device__ __forceinline__ bf16_t f2b(float f) {
  unsigned u = __float_as_uint(f);
  unsigned r = (u + 0x7FFFu + ((u >> 16) & 1u)) >> 16;
  return (bf16_t)r;
}
__device__ __forceinline__ float ldf(const float* p) { return *p; }
__device__ __forceinline__ float ldf(const bf16_t* p) { return b2f(*p); }
__device__ __forceinline__ void stf(float* p, float v) { *p = v; }
__device__ __forceinline__ void stf(bf16_t* p, float v) { *p = f2b(v); }

__device__ __forceinline__ void ldv4(const float* p, float* v) {
  float4 t = *(const float4*)p;
  v[0] = t.x; v[1] = t.y; v[2] = t.z; v[3] = t.w;
}
__device__ __forceinline__ void ldv4(const bf16_t* p, float* v) {
  ushort4 t = *(const ushort4*)p;
  v[0] = b2f(t.x); v[1] = b2f(t.y); v[2] = b2f(t.z); v[3] = b2f(t.w);
}
__device__ __forceinline__ void stv4(float* p, const float* v) {
  float4 t; t.x = v[0]; t.y = v[1]; t.z = v[2]; t.w = v[3];
  *(float4*)p = t;
}
__device__ __forceinline__ void stv4(bf16_t* p, const float* v) {
  ushort4 t; t.x = f2b(v[0]); t.y = f2b(v[1]); t.z = f2b(v[2]); t.w = f2b(v[3]);
  *(ushort4*)p = t;
}

__device__ __forceinline__ float gelu_f(float x) {
  return 0.5f * x * (1.0f + erff(x * 0.7071067811865475f));
}

__device__ __forceinline__ void unpack8(uint4 v, float* rv) {
  unsigned wv[4] = {v.x, v.y, v.z, v.w};
#pragma unroll
  for (int j = 0; j < 8; ++j)
    rv[j + 1] = b2f((bf16_t)((wv[j >> 1] >> ((j & 1) * 16)) & 0xFFFFu));
}
__device__ __forceinline__ uint4 pack8(const float* a) {
  uint4 o;
  unsigned w[4];
#pragma unroll
  for (int p = 0; p < 4; ++p) {
    unsigned lo = f2b(a[2 * p]), hi = f2b(a[2 * p + 1]);
    w[p] = lo | (hi << 16);
  }
  o.x = w[0]; o.y = w[1]; o.z = w[2]; o.w = w[3];
  return o;
}

// ---------------- workspace layout (byte offsets) ----------------
constexpr size_t oATTRAW  = 0;
constexpr size_t oATTS    = 1327104;
constexpr size_t oNORMQ   = 1363968;
constexpr size_t oNORMK   = 1364992;
constexpr size_t oIDX     = 1366016;
constexpr size_t oMU      = 1366528;
constexpr size_t oCOV     = 1367040;
constexpr size_t oQKV     = 1572864;           // 56,623,104 B (bf16 2*384*36864)
constexpr size_t oXN      = 58195968;          // 18,874,368 B  xn / qk-partial / x1b
constexpr size_t oOUTALL  = 77070336;          // 18,874,368 B
constexpr size_t oSBUF    = 95944704;          // 18,874,368 B
constexpr size_t WS_NEED  = 114819072;
// aliases:
constexpr size_t oCHUNK1  = oOUTALL;           // 28,311,552 B used (192ch chunks, spans into SBUF — dead)
constexpr size_t oCOVPART = oOUTALL;           // 37,748,736 B (spans OUTALL+SBUF, both dead)
constexpr size_t oQKPART  = oXN;
constexpr size_t oGATED   = oQKV;
constexpr size_t oDBUF    = oQKV + 18874368;
constexpr size_t oY0C     = oOUTALL;           // 25,067,520 B (spans into oSBUF, both dead)
constexpr size_t oZ       = oQKV;
constexpr size_t oX1B     = oXN;               // bf16 x1 (xn/qkpart dead)

// ---------------- LayerNorm over channel dim (templated input) ----------------
template <typename TI>
__global__ __launch_bounds__(TPB) void k_ln(const TI* __restrict__ x,
                                            const float* __restrict__ w,
                                            const float* __restrict__ bias,
                                            bf16_t* __restrict__ out) {
  int t = blockIdx.x * TPB + threadIdx.x;
  if (t >= BN_ * HWc) return;
  int b = t / HWc, l = t - b * HWc;
  const TI* xb = x + (size_t)b * CDIM * HWc + l;
  float s = 0.f, s2 = 0.f;
#pragma unroll 4
  for (int c = 0; c < CDIM; ++c) { float v = ldf(&xb[(size_t)c * HWc]); s += v; s2 += v * v; }
  float mu  = s * (1.f / CDIM);
  float var = s2 * (1.f / CDIM) - mu * mu;
  float inv = 1.f / sqrtf(var + 1e-5f);
  bf16_t* ob = out + (size_t)b * CDIM * HWc + l;
#pragma unroll 4
  for (int c = 0; c < CDIM; ++c)
    stf(&ob[(size_t)c * HWc], (ldf(&xb[(size_t)c * HWc]) - mu) * inv * w[c] + bias[c]);
}

// ============ MFMA channel GEMM, ACT-RESIDENT (K = KT <= 128) ============
// Block owns one 128-l tile. Stages full [KT][128] act panel ONCE, then loops
// o-chunks of 64, staging W per chunk. out[b,o,l] = sum_c Wrow(o)[c] in[b,c,l].
// Wrow(o) = o<osplit ? W+o*KT : W2+(o-osplit)*KT.
// EPI: 0 = (+bias), 1 = (+bias)+aux, 2 = gelu(+bias)*aux
template <typename TO, typename TA, int KT, int EPI>
__global__ __launch_bounds__(TPB) void k_mgA(const float* __restrict__ W,
                                             const float* __restrict__ W2, int osplit,
                                             const float* __restrict__ bias,
                                             const bf16_t* __restrict__ in,
                                             const TA* __restrict__ aux,
                                             TO* __restrict__ out, int O,
                                             int ibr, int obr, int abr) {
  constexpr int L  = HWc;
  constexpr int PK = KT + 8;
  constexpr int KH = KT / 2;
  constexpr int SH = (KT == 128) ? 6 : 5;   // log2(KH)
  __shared__ bf16_t At[128 * PK];
  __shared__ bf16_t Wt[64 * PK];
  int b = blockIdx.y;
  const bf16_t* inb  = in  + (size_t)b * ibr * L;
  const TA*     auxb = aux ? aux + (size_t)b * abr * L : nullptr;
  TO*           outb = out + (size_t)b * obr * L;
  int l0 = blockIdx.x * 128;
  int tid = threadIdx.x, lane = tid & 63, wid = tid >> 6;
  int wm = wid >> 1, wn = wid & 1;          // 2x2 wave grid, wave tile 32(O)x64(L)
  int cl = lane & 15, rg = lane >> 4;

  // ---- stage act panel [KT][128] -> At[l][k], once ----
#pragma unroll
  for (int r = 0; r < (KH * 16) / TPB; ++r) {
    int u  = tid + r * TPB;
    int k2 = u & (KH - 1), lb = u >> SH;
    int ka = k2 * 2;
    uint4 rowA = *(const uint4*)(&inb[(size_t)ka * L + l0 + lb * 8]);
    uint4 rowB = *(const uint4*)(&inb[(size_t)(ka + 1) * L + l0 + lb * 8]);
    unsigned wa[4] = {rowA.x, rowA.y, rowA.z, rowA.w};
    unsigned wb[4] = {rowB.x, rowB.y, rowB.z, rowB.w};
#pragma unroll
    for (int j = 0; j < 8; ++j) {
      unsigned va = (wa[j >> 1] >> ((j & 1) * 16)) & 0xFFFFu;
      unsigned vb = (wb[j >> 1] >> ((j & 1) * 16)) & 0xFFFFu;
      *(unsigned*)(&At[(lb * 8 + j) * PK + ka]) = va | (vb << 16);
    }
  }

  int noc = (O + 63) >> 6;
  for (int oc = 0; oc < noc; ++oc) {
    int o0 = oc * 64;
    // ---- stage W rows [o0,o0+64) x KT -> Wt (fp32 -> bf16) ----
#pragma unroll
    for (int r = 0; r < (64 * KT / 4) / TPB; ++r) {
      int e = tid + r * TPB;
      int o = e / (KT / 4), k4 = (e % (KT / 4)) * 4;
      int og = o0 + o;
      float w0 = 0.f, w1 = 0.f, w2 = 0.f, w3 = 0.f;
      if (og < O) {
        const float* wrow = (og < osplit) ? (W + (size_t)og * KT)
                                          : (W2 + (size_t)(og - osplit) * KT);
        w0 = wrow[k4]; w1 = wrow[k4 + 1]; w2 = wrow[k4 + 2]; w3 = wrow[k4 + 3];
      }
      ushort4 pk;
      pk.x = f2b(w0); pk.y = f2b(w1); pk.z = f2b(w2); pk.w = f2b(w3);
      *(ushort4*)(&Wt[o * PK + k4]) = pk;
    }
    __syncthreads();
    // ---- MFMA: D[l][o] ----
    f32x4 acc[2][4];
#pragma unroll
    for (int m = 0; m < 2; ++m)
#pragma unroll
      for (int n = 0; n < 4; ++n) acc[m][n] = (f32x4){0.f, 0.f, 0.f, 0.f};
#pragma unroll
    for (int kk = 0; kk < KT / 32; ++kk) {
      int kof = kk * 32 + rg * 8;
      bf16x8 a[2], bfr[4];
#pragma unroll
      for (int m = 0; m < 2; ++m)
        a[m] = *(const bf16x8*)(&Wt[(wm * 32 + m * 16 + cl) * PK + kof]);
#pragma unroll
      for (int n = 0; n < 4; ++n)
        bfr[n] = *(const bf16x8*)(&At[(wn * 64 + n * 16 + cl) * PK + kof]);
#pragma unroll
      for (int m = 0; m < 2; ++m)
#pragma unroll
        for (int n = 0; n < 4; ++n)
          acc[m][n] = __builtin_amdgcn_mfma_f32_16x16x32_bf16(bfr[n], a[m], acc[m][n], 0, 0, 0);
    }
    __syncthreads();   // Wt consumed; safe to restage next oc (epilogue overlaps)
    // ---- epilogue: thread holds 4 consecutive l at fixed o => vector I/O ----
#pragma unroll
    for (int m = 0; m < 2; ++m) {
      int og = o0 + wm * 32 + m * 16 + cl;
      if (og >= O) continue;
      float bv = bias ? bias[og] : 0.f;
#pragma unroll
      for (int n = 0; n < 4; ++n) {
        int lcol = l0 + wn * 64 + n * 16 + rg * 4;
        size_t off = (size_t)og * L + lcol;
        float v[4];
#pragma unroll
        for (int r = 0; r < 4; ++r) v[r] = acc[m][n][r] + bv;
        if (EPI == 1) {
          float a4[4]; ldv4(&auxb[off], a4);
#pragma unroll
          for (int r = 0; r < 4; ++r) v[r] += a4[r];
        } else if (EPI == 2) {
          float a4[4]; ldv4(&auxb[off], a4);
#pragma unroll
          for (int r = 0; r < 4; ++r) v[r] = gelu_f(v[r]) * a4[r];
        }
        stv4(&outb[off], v);
      }
    }
  }
}

// ============ MFMA channel GEMM, K-LOOP with O=128 resident in regs ============
// For ffn_out: K=340, O=128. Act staged per K-step (read once from HBM);
// both 64-row o-chunks accumulate in registers (acc[4][4]).
template <typename TO, typename TA, int EPI>
__global__ __launch_bounds__(TPB) void k_mgB(const float* __restrict__ W,
                                             const float* __restrict__ bias,
                                             const bf16_t* __restrict__ in,
                                             const TA* __restrict__ aux,
                                             TO* __restrict__ out, int O, int K,
                                             int ibr, int obr, int abr) {
  constexpr int L = HWc;
  constexpr int PK = 72, BK = 64;
  __shared__ bf16_t At[128 * PK];
  __shared__ bf16_t Wt[128 * PK];
  int b = blockIdx.y;
  const bf16_t* inb  = in  + (size_t)b * ibr * L;
  const TA*     auxb = aux ? aux + (size_t)b * abr * L : nullptr;
  TO*           outb = out + (size_t)b * obr * L;
  int l0 = blockIdx.x * 128;
  int tid = threadIdx.x, lane = tid & 63, wid = tid >> 6;
  int wm = wid >> 1, wn = wid & 1;          // wave tile 64(O) x 64(L)
  int cl = lane & 15, rg = lane >> 4;

  f32x4 acc[4][4];
#pragma unroll
  for (int m = 0; m < 4; ++m)
#pragma unroll
    for (int n = 0; n < 4; ++n) acc[m][n] = (f32x4){0.f, 0.f, 0.f, 0.f};

  for (int k0 = 0; k0 < K; k0 += BK) {
    // ---- stage act [BK][128] -> At[l][k] ----
#pragma unroll
    for (int r = 0; r < 2; ++r) {
      int u = tid + r * TPB;
      int k2 = u & 31, lb = u >> 5;
      int ka = k0 + k2 * 2;
      uint4 rowA = {0u,0u,0u,0u}, rowB = {0u,0u,0u,0u};
      if (ka < K)     rowA = *(const uint4*)(&inb[(size_t)ka * L + l0 + lb * 8]);
      if (ka + 1 < K) rowB = *(const uint4*)(&inb[(size_t)(ka + 1) * L + l0 + lb * 8]);
      unsigned wa[4] = {rowA.x, rowA.y, rowA.z, rowA.w};
      unsigned wb[4] = {rowB.x, rowB.y, rowB.z, rowB.w};
#pragma unroll
      for (int j = 0; j < 8; ++j) {
        unsigned va = (wa[j >> 1] >> ((j & 1) * 16)) & 0xFFFFu;
        unsigned vb = (wb[j >> 1] >> ((j & 1) * 16)) & 0xFFFFu;
        *(unsigned*)(&At[(lb * 8 + j) * PK + k2 * 2]) = va | (vb << 16);
      }
    }
    // ---- stage W [128][BK] -> Wt ----
#pragma unroll
    for (int r = 0; r < 8; ++r) {
      int e = tid + r * TPB;
      int o = e >> 4, k4 = (e & 15) * 4;
      float w0 = 0.f, w1 = 0.f, w2 = 0.f, w3 = 0.f;
      if (o < O) {
        const float* wrow = W + (size_t)o * K + k0 + k4;
        if (k0 + k4 + 0 < K) w0 = wrow[0];
        if (k0 + k4 + 1 < K) w1 = wrow[1];
        if (k0 + k4 + 2 < K) w2 = wrow[2];
        if (k0 + k4 + 3 < K) w3 = wrow[3];
      }
      ushort4 pk;
      pk.x = f2b(w0); pk.y = f2b(w1); pk.z = f2b(w2); pk.w = f2b(w3);
      *(ushort4*)(&Wt[o * PK + k4]) = pk;
    }
    __syncthreads();
#pragma unroll
    for (int kk = 0; kk < 2; ++kk) {
      int kof = kk * 32 + rg * 8;
      bf16x8 a[4], bfr[4];
#pragma unroll
      for (int m = 0; m < 4; ++m)
        a[m] = *(const bf16x8*)(&Wt[(wm * 64 + m * 16 + cl) * PK + kof]);
#pragma unroll
      for (int n = 0; n < 4; ++n)
        bfr[n] = *(const bf16x8*)(&At[(wn * 64 + n * 16 + cl) * PK + kof]);
#pragma unroll
      for (int m = 0; m < 4; ++m)
#pragma unroll
        for (int n = 0; n < 4; ++n)
          acc[m][n] = __builtin_amdgcn_mfma_f32_16x16x32_bf16(bfr[n], a[m], acc[m][n], 0, 0, 0);
    }
    __syncthreads();
  }
  // ---- epilogue ----
#pragma unroll
  for (int m = 0; m < 4; ++m) {
    int og = wm * 64 + m * 16 + cl;
    if (og >= O) continue;
    float bv = bias ? bias[og] : 0.f;
#pragma unroll
    for (int n = 0; n < 4; ++n) {
      int lcol = l0 + wn * 64 + n * 16 + rg * 4;
      size_t off = (size_t)og * L + lcol;
      float v[4];
#pragma unroll
      for (int r = 0; r < 4; ++r) v[r] = acc[m][n][r] + bv;
      if (EPI == 1) {
        float a4[4]; ldv4(&auxb[off], a4);
#pragma unroll
        for (int r = 0; r < 4; ++r) v[r] += a4[r];
      } else if (EPI == 2) {
        float a4[4]; ldv4(&auxb[off], a4);
#pragma unroll
        for (int r = 0; r < 4; ++r) v[r] = gelu_f(v[r]) * a4[r];
      }
      stv4(&outb[off], v);
    }
  }
}

// ---------------- depthwise 3x3 SAME, vectorized 8 px/thread ----------------
__global__ __launch_bounds__(TPB) void k_dw3v(const bf16_t* __restrict__ in,
                                              const float* __restrict__ wt,
                                              bf16_t* __restrict__ out,
                                              int Cc, int c0, int CoutTotal, long totalG) {
  long t = (long)blockIdx.x * TPB + threadIdx.x;
  if (t >= totalG) return;
  int g = (int)(t % (HWc / 8));
  long bc = t / (HWc / 8);
  int cl = (int)(bc % Cc);
  int b = (int)(bc / Cc);
  int h = g / (WW / 8), w8 = (g % (WW / 8)) * 8;
  const bf16_t* ib = in + ((size_t)b * Cc + cl) * HWc;
  const float* wc = wt + (size_t)(c0 + cl) * 9;
  float rowv[3][10];
#pragma unroll
  for (int dy = -1; dy <= 1; ++dy) {
    float* rv = rowv[dy + 1];
    int hh = h + dy;
    if ((unsigned)hh >= (unsigned)HH) {
#pragma unroll
      for (int j = 0; j < 10; ++j) rv[j] = 0.f;
      continue;
    }
    const bf16_t* rp = ib + hh * WW + w8;
    unpack8(*(const uint4*)rp, rv);
    rv[0] = (w8 > 0) ? b2f(rp[-1]) : 0.f;
    rv[9] = (w8 + 8 < WW) ? b2f(rp[8]) : 0.f;
  }
  float a[8];
#pragma unroll
  for (int j = 0; j < 8; ++j) {
    float s = 0.f;
#pragma unroll
    for (int dy = 0; dy < 3; ++dy)
#pragma unroll
      for (int dx = 0; dx < 3; ++dx)
        s += rowv[dy][j + dx] * wc[dy * 3 + dx];
    a[j] = s;
  }
  *(uint4*)(&out[((size_t)b * CoutTotal + c0 + cl) * HWc + h * WW + w8]) = pack8(a);
}

// ---------------- mu over cf = 0.5*(q_b0+q_b1) ----------------
__global__ __launch_bounds__(TPB) void k_mu(const bf16_t* __restrict__ qkv, float* __restrict__ mu) {
  int c = blockIdx.x;
  __shared__ float red[TPB];
  float s = 0.f;
  for (int l = threadIdx.x; l < HWc; l += TPB)
    s += 0.5f * (b2f(qkv[(size_t)c * HWc + l]) + b2f(qkv[(size_t)C3 * HWc + (size_t)c * HWc + l]));
  red[threadIdx.x] = s;
  __syncthreads();
  for (int st = TPB / 2; st > 0; st >>= 1) {
    if (threadIdx.x < st) red[threadIdx.x] += red[threadIdx.x + st];
    __syncthreads();
  }
  if (threadIdx.x == 0) mu[c] = red[0] / HWc;
}

// ---------------- split-L cov partials (576 chunks x 64 cols, conflict-free) --------
__global__ __launch_bounds__(TPB) void k_cov3(const bf16_t* __restrict__ qkv,
                                              float* __restrict__ part) {
  int chunk = blockIdx.x;
  int tid = threadIdx.x, ti = tid & 15, tj = tid >> 4;
  __shared__ float xs[CDIM][65];
  int base = chunk * CV3L;
#pragma unroll
  for (int r4 = 0; r4 < 4; ++r4) {
    int u = tid + r4 * 256;
    int r = u >> 3, c8 = (u & 7) * 8;
    uint4 vq = *(const uint4*)(&qkv[(size_t)r * HWc + base + c8]);
    uint4 vk = *(const uint4*)(&qkv[(size_t)C3 * HWc + (size_t)r * HWc + base + c8]);
    unsigned wq[4] = {vq.x, vq.y, vq.z, vq.w};
    unsigned wk[4] = {vk.x, vk.y, vk.z, vk.w};
#pragma unroll
    for (int j = 0; j < 8; ++j) {
      float q = b2f((bf16_t)((wq[j >> 1] >> ((j & 1) * 16)) & 0xFFFFu));
      float k = b2f((bf16_t)((wk[j >> 1] >> ((j & 1) * 16)) & 0xFFFFu));
      xs[r][c8 + j] = 0.5f * (q + k);
    }
  }
  __syncthreads();
  float acc[8][8];
#pragma unroll
  for (int m = 0; m < 8; ++m)
#pragma unroll
    for (int n = 0; n < 8; ++n) acc[m][n] = 0.f;
#pragma unroll 2
  for (int l = 0; l < CV3L; ++l) {
    float a[8], b[8];
#pragma unroll
    for (int m = 0; m < 8; ++m) a[m] = xs[ti + 16 * m][l];
#pragma unroll
    for (int n = 0; n < 8; ++n) b[n] = xs[tj + 16 * n][l];
#pragma unroll
    for (int m = 0; m < 8; ++m)
#pragma unroll
      for (int n = 0; n < 8; ++n) acc[m][n] += a[m] * b[n];
  }
  float* pb = part + (size_t)chunk * CDIM * CDIM;
#pragma unroll
  for (int m = 0; m < 8; ++m)
#pragma unroll
    for (int n = 0; n < 8; ++n)
      pb[(ti + 16 * m) * CDIM + tj + 16 * n] = acc[m][n];
}

// ---------------- reduce cov partials + mean correction ----------------
__global__ __launch_bounds__(TPB) void k_covred(const float* __restrict__ part,
                                                const float* __restrict__ mu,
                                                float* __restrict__ cov) {
  int t = blockIdx.x * TPB + threadIdx.x;
  if (t >= CDIM * CDIM) return;
  float s = 0.f;
  for (int p = 0; p < CV3; ++p) s += part[(size_t)p * CDIM * CDIM + t];
  int c = t >> 7, d = t & 127;
  cov[t] = s - (float)HWc * mu[c] * mu[d];
}

// ---------------- parallel stable rank ----------------
__global__ __launch_bounds__(CDIM) void k_rank(const float* __restrict__ cov,
                                               int* __restrict__ idx) {
  __shared__ float dsd[CDIM], score[CDIM];
  int tid = threadIdx.x;
  dsd[tid] = sqrtf(cov[tid * CDIM + tid]);
  __syncthreads();
  {
    float s = 0.f, di = dsd[tid];
    for (int d = 0; d < CDIM; ++d) s += cov[tid * CDIM + d] / (di * dsd[d]);
    score[tid] = s;
  }
  __syncthreads();
  {
    float my = score[tid];
    int rank = 0;
    for (int d = 0; d < CDIM; ++d)
      rank += (score[d] > my) || (score[d] == my && d < tid);
    idx[rank] = tid;
  }
}

// ---------------- row norms of permuted q,k ----------------
__global__ __launch_bounds__(TPB) void k_norms(const bf16_t* __restrict__ qkv,
                                               const int* __restrict__ idx,
                                               float* __restrict__ normq,
                                               float* __restrict__ normk) {
  int p = blockIdx.x, b = blockIdx.y, which = blockIdx.z;
  int ch = idx[p] + which * CDIM;
  const bf16_t* row = qkv + ((size_t)b * C3 + ch) * HWc;
  __shared__ float red[TPB];
  float s = 0.f;
  for (int l = threadIdx.x; l < HWc; l += TPB) { float v = b2f(row[l]); s += v * v; }
  red[threadIdx.x] = s;
  __syncthreads();
  for (int st = TPB / 2; st > 0; st >>= 1) {
    if (threadIdx.x < st) red[threadIdx.x] += red[threadIdx.x + st];
    __syncthreads();
  }
  if (threadIdx.x == 0) {
    float n = fmaxf(sqrtf(red[0]), 1e-12f);
    (which ? normk : normq)[b * CDIM + p] = n;
  }
}

// ---------------- QK^T split-L partials ----------------
template <int G>
__global__ __launch_bounds__(TPB) void k_qk2(const bf16_t* __restrict__ qkv,
                                             const int* __restrict__ idx, int start,
                                             float* __restrict__ partial) {
  constexpr int RT = G / 16;
  constexpr int U  = G * CH2 / 8;
  int nl = blockIdx.x, b = blockIdx.y;
  __shared__ float qs[G][CH2 + 2], ks[G][CH2 + 2];
  __shared__ int idxg[G];
  int tid = threadIdx.x;
  if (tid < G) idxg[tid] = idx[start + tid];
  __syncthreads();
  int l0 = nl * CH2;
  for (int u = tid; u < U; u += TPB) {
    int r = u / (CH2 / 8), c8 = (u % (CH2 / 8)) * 8;
    int ch = idxg[r];
    uint4 vq = *(const uint4*)(&qkv[((size_t)b * C3 + ch) * HWc + l0 + c8]);
    uint4 vk = *(const uint4*)(&qkv[((size_t)b * C3 + CDIM + ch) * HWc + l0 + c8]);
    unsigned wq[4] = {vq.x, vq.y, vq.z, vq.w};
    unsigned wk[4] = {vk.x, vk.y, vk.z, vk.w};
#pragma unroll
    for (int j = 0; j < 8; ++j) {
      qs[r][c8 + j] = b2f((bf16_t)((wq[j >> 1] >> ((j & 1) * 16)) & 0xFFFFu));
      ks[r][c8 + j] = b2f((bf16_t)((wk[j >> 1] >> ((j & 1) * 16)) & 0xFFFFu));
    }
  }
  __syncthreads();
  int ti = tid & 15, tj = tid >> 4;
  float acc[RT][RT];
#pragma unroll
  for (int m = 0; m < RT; ++m)
#pragma unroll
    for (int n = 0; n < RT; ++n) acc[m][n] = 0.f;
#pragma unroll 4
  for (int l = 0; l < CH2; ++l) {
    float qa[RT], kb[RT];
#pragma unroll
    for (int m = 0; m < RT; ++m) qa[m] = qs[ti * RT + m][l];
#pragma unroll
    for (int n = 0; n < RT; ++n) kb[n] = ks[tj * RT + n][l];
#pragma unroll
    for (int m = 0; m < RT; ++m)
#pragma unroll
      for (int n = 0; n < RT; ++n) acc[m][n] += qa[m] * kb[n];
  }
  float* pb = partial + ((size_t)(b * NL2) + nl) * G * G;
#pragma unroll
  for (int m = 0; m < RT; ++m)
#pragma unroll
    for (int n = 0; n < RT; ++n)
      pb[(ti * RT + m) * G + tj * RT + n] = acc[m][n];
}

// ---------------- reduce QK^T partials over chunks ----------------
__global__ __launch_bounds__(TPB) void k_qkred(const float* __restrict__ partial,
                                               float* __restrict__ attraw, int GG) {
  int t = blockIdx.x * TPB + threadIdx.x;
  if (t >= BN_ * GG) return;
  int b = t / GG, e = t - b * GG;
  const float* pb = partial + (size_t)b * NL2 * GG + e;
  float s = 0.f;
  for (int nl = 0; nl < NL2; ++nl) s += pb[(size_t)nl * GG];
  attraw[t] = s;
}

// ---------------- per-group softmax + pooled-cache MLP ----------------
template <int G>
__global__ __launch_bounds__(TPB) void k_inter(const float* __restrict__ attraw,
                                               const float* __restrict__ normq,
                                               const float* __restrict__ normk, int start,
                                               const float* __restrict__ temperature, int gi,
                                               const float* __restrict__ qv_cache,
                                               const float* __restrict__ cw_w,
                                               const float* __restrict__ cw_b,
                                               const float* __restrict__ g_w,
                                               const float* __restrict__ g_b,
                                               float* __restrict__ attF) {
  constexpr int GG = G * G;
  int b = blockIdx.x;
  __shared__ float att[GG], t1[GG], sc[GG], sh[GG], x1p[GG], t2[GG];
  int tid = threadIdx.x;
  float temp = temperature[gi];
  for (int e = tid; e < GG; e += TPB) {
    int i = e / G, j = e % G;
    att[e] = attraw[b * GG + e] * temp /
             (normq[b * CDIM + start + i] * normk[b * CDIM + start + j]);
  }
  __syncthreads();
  if (tid < G) {
    float mx = -3.4e38f;
    for (int j = 0; j < G; ++j) mx = fmaxf(mx, att[tid * G + j]);
    float ssum = 0.f;
    for (int j = 0; j < G; ++j) { float ex = expf(att[tid * G + j] - mx); att[tid * G + j] = ex; ssum += ex; }
    float inv = 1.f / ssum;
    for (int j = 0; j < G; ++j) att[tid * G + j] *= inv;
  }
  __syncthreads();
  for (int e = tid; e < GG; e += TPB) {
    int o = e / G, p = e % G;
    int so = o * CDIM / G, eo = ((o + 1) * CDIM + G - 1) / G;
    int sp = p * CDIM / G, ep = ((p + 1) * CDIM + G - 1) / G;
    float ssum = 0.f;
    for (int i2 = so; i2 < eo; ++i2)
      for (int j2 = sp; j2 < ep; ++j2) ssum += qv_cache[i2 * CDIM + j2];
    t1[e] = ssum / (float)((eo - so) * (ep - sp)) + att[e];
  }
  __syncthreads();
  for (int e = tid; e < 2 * GG; e += TPB) {
    int o = e / G, p = e % G;
    float v = cw_b[o];
    for (int c = 0; c < G; ++c) v += cw_w[o * G + c] * t1[c * G + p];
    if (o < G) sc[o * G + p] = v; else sh[(o - G) * G + p] = v;
  }
  __syncthreads();
  for (int e = tid; e < GG; e += TPB) x1p[e] = att[e] * sc[e] + sh[e];
  __syncthreads();
  for (int e = tid; e < GG; e += TPB) {
    int o = e / G, p = e % G;
    float v = g_b[o];
    for (int c = 0; c < G; ++c) v += g_w[o * G + c] * x1p[c * G + p];
    t2[e] = v;
  }
  __syncthreads();
  for (int e = tid; e < GG; e += TPB)
    attF[(size_t)b * GG + e] = x1p[e] * gelu_f(t2[e]) + att[e];
}

// ---------------- att @ V + (qn+kn) fused ----------------
template <int G>
__global__ __launch_bounds__(TPB) void k_av(const bf16_t* __restrict__ qkv,
                                            const int* __restrict__ idx,
                                            const float* __restrict__ attF,
                                            const float* __restrict__ normq,
                                            const float* __restrict__ normk, int start,
                                            bf16_t* __restrict__ out_all,
                                            bf16_t* __restrict__ s_buf) {
  constexpr int GH = G / 2;
  int b = blockIdx.y;
  int l0 = blockIdx.x * 128;
  __shared__ float vt[G][129];
  __shared__ float attL[G * G];
  __shared__ int idxg[G];
  int tid = threadIdx.x;
  if (tid < G) idxg[tid] = idx[start + tid];
  for (int e = tid; e < G * G; e += TPB) attL[e] = attF[(size_t)b * G * G + e];
  __syncthreads();
  for (int e = tid; e < G * 128; e += TPB) {
    int j = e >> 7, c = e & 127;
    vt[j][c] = b2f(qkv[((size_t)b * C3 + 2 * CDIM + idxg[j]) * HWc + l0 + c]);
  }
  __syncthreads();
  int ll = tid & 127, half = tid >> 7;
  float acc[GH];
#pragma unroll
  for (int i = 0; i < GH; ++i) acc[i] = 0.f;
  for (int j = 0; j < G; ++j) {
    float vv = vt[j][ll];
#pragma unroll
    for (int i = 0; i < GH; ++i) acc[i] += attL[(half * GH + i) * G + j] * vv;
  }
#pragma unroll
  for (int i = 0; i < GH; ++i) {
    int ig = half * GH + i;
    int p = start + ig;
    int ch = idxg[ig];
    float qv = b2f(qkv[((size_t)b * C3 + ch) * HWc + l0 + ll]);
    float kv = b2f(qkv[((size_t)b * C3 + CDIM + ch) * HWc + l0 + ll]);
    float tmp = qv / normq[b * CDIM + p] + kv / normk[b * CDIM + p];
    size_t off = ((size_t)b * CDIM + p) * HWc + l0 + ll;
    stf(&out_all[off], acc[i]);
    stf(&s_buf[off], acc[i] + tmp);
  }
}

// ---------------- qv_new: bilinear upsample + floor + EMA ----------------
__global__ __launch_bounds__(TPB) void k_qvnew(const float* __restrict__ attsF,
                                               const float* __restrict__ qv_cache,
                                               float* __restrict__ out_qv) {
  int t = blockIdx.x * TPB + threadIdx.x;
  if (t >= CDIM * CDIM) return;
  int r = t >> 7, cq = t & 127;
  const int gs[4]   = {16, 32, 32, 48};
  const int base[4] = {0, 512, 2560, 4608};
  float acc = 0.f;
  for (int gi = 0; gi < 4; ++gi) {
    int g = gs[gi], gg = g * g;
    const float* a0 = attsF + base[gi];
    float scale = (float)g / CDIM;
    float fr = (r + 0.5f) * scale - 0.5f;
    float fc = (cq + 0.5f) * scale - 0.5f;
    float flr = floorf(fr), flc = floorf(fc);
    int i0 = (int)flr, j0 = (int)flc;
    float wr = fr - flr, wcw = fc - flc;
    int i0c = max(i0, 0), i1c = min(i0 + 1, g - 1);
    int j0c = max(j0, 0), j1c = min(j0 + 1, g - 1);
    float m00 = 0.5f * (a0[i0c * g + j0c] + a0[gg + i0c * g + j0c]);
    float m01 = 0.5f * (a0[i0c * g + j1c] + a0[gg + i0c * g + j1c]);
    float m10 = 0.5f * (a0[i1c * g + j0c] + a0[gg + i1c * g + j0c]);
    float m11 = 0.5f * (a0[i1c * g + j1c] + a0[gg + i1c * g + j1c]);
    float val = (1.f - wr) * ((1.f - wcw) * m00 + wcw * m01)
              + wr * ((1.f - wcw) * m10 + wcw * m11);
    acc += floorf(val);
  }
  out_qv[t] = qv_cache[t] * 0.9f + acc * 0.1f;
}

// ---------------- ffn: dw3 pair + gelu-gate, vectorized 8 px/thread ----------------
__global__ __launch_bounds__(TPB) void k_dwgeluv(const bf16_t* __restrict__ y0c,
                                                 const float* __restrict__ wt,
                                                 bf16_t* __restrict__ z,
                                                 int Cc, int c0, long totalG) {
  long t = (long)blockIdx.x * TPB + threadIdx.x;
  if (t >= totalG) return;
  int g = (int)(t % (HWc / 8));
  long bc = t / (HWc / 8);
  int cl = (int)(bc % Cc);
  int b = (int)(bc / Cc);
  int h = g / (WW / 8), w8 = (g % (WW / 8)) * 8;
  const bf16_t* i1 = y0c + ((size_t)b * 2 * Cc + cl) * HWc;
  const bf16_t* i2 = y0c + ((size_t)b * 2 * Cc + Cc + cl) * HWc;
  const float* w1 = wt + (size_t)(c0 + cl) * 9;
  const float* w2 = wt + (size_t)(HID + c0 + cl) * 9;
  float r1[3][10], r2[3][10];
#pragma unroll
  for (int dy = -1; dy <= 1; ++dy) {
    float* v1 = r1[dy + 1];
    float* v2 = r2[dy + 1];
    int hh = h + dy;
    if ((unsigned)hh >= (unsigned)HH) {
#pragma unroll
      for (int j = 0; j < 10; ++j) { v1[j] = 0.f; v2[j] = 0.f; }
      continue;
    }
    const bf16_t* p1 = i1 + hh * WW + w8;
    const bf16_t* p2 = i2 + hh * WW + w8;
    unpack8(*(const uint4*)p1, v1);
    unpack8(*(const uint4*)p2, v2);
    bool hasL = (w8 > 0), hasR = (w8 + 8 < WW);
    v1[0] = hasL ? b2f(p1[-1]) : 0.f;
    v1[9] = hasR ? b2f(p1[8]) : 0.f;
    v2[0] = hasL ? b2f(p2[-1]) : 0.f;
    v2[9] = hasR ? b2f(p2[8]) : 0.f;
  }
  float o[8];
#pragma unroll
  for (int j = 0; j < 8; ++j) {
    float a1 = 0.f, a2 = 0.f;
#pragma unroll
    for (int dy = 0; dy < 3; ++dy)
#pragma unroll
      for (int dx = 0; dx < 3; ++dx) {
        a1 += r1[dy][j + dx] * w1[dy * 3 + dx];
        a2 += r2[dy][j + dx] * w2[dy * 3 + dx];
      }
    o[j] = gelu_f(a1) * a2;
  }
  *(uint4*)(&z[((size_t)b * HID + c0 + cl) * HWc + h * WW + w8]) = pack8(o);
}

// ---------------- host ----------------
extern "C" void kernel_launch(void* const* d_in, const int* in_sizes, int n_in,
                              void* d_out, int out_size, void* d_ws, size_t ws_size,
                              hipStream_t stream) {
  if (ws_size < WS_NEED) return;  // workspace insufficient

  const float* x        = (const float*)d_in[0];
  const float* qv_cache = (const float*)d_in[1];
  const float* ln1_w    = (const float*)d_in[2];
  const float* ln1_b    = (const float*)d_in[3];
  const float* ln2_w    = (const float*)d_in[4];
  const float* ln2_b    = (const float*)d_in[5];
  const float* temperature = (const float*)d_in[6];
  const float* w_qkv    = (const float*)d_in[7];
  const float* w_qkv_dw = (const float*)d_in[8];
  const float* w_proj   = (const float*)d_in[9];
  const float* intra_down_w = (const float*)d_in[10];
  const float* intra_down_b = (const float*)d_in[11];
  const float* intra_up_w   = (const float*)d_in[12];
  const float* intra_up_b   = (const float*)d_in[13];
  const float* intra_gate_w = (const float*)d_in[14];
  const float* intra_gate_b = (const float*)d_in[15];
  const float* ffn_in_w  = (const float*)d_in[32];
  const float* ffn_dw_w  = (const float*)d_in[33];
  const float* ffn_out_w = (const float*)d_in[34];

  char* wsb = (char*)d_ws;
  float* out    = (float*)d_out;
  float* out_qv = out + (size_t)BN_ * CDIM * HWc;
  bf16_t* xn2   = (bf16_t*)d_out;   // scratch in d_out's out-region (dead before final write)

  float*  attraw  = (float*)(wsb + oATTRAW);
  float*  atts    = (float*)(wsb + oATTS);
  float*  normq   = (float*)(wsb + oNORMQ);
  float*  normk   = (float*)(wsb + oNORMK);
  int*    idx     = (int*)(wsb + oIDX);
  float*  mu      = (float*)(wsb + oMU);
  float*  cov     = (float*)(wsb + oCOV);
  bf16_t* qkv     = (bf16_t*)(wsb + oQKV);
  bf16_t* xn      = (bf16_t*)(wsb + oXN);
  bf16_t* out_all = (bf16_t*)(wsb + oOUTALL);
  bf16_t* sbuf    = (bf16_t*)(wsb + oSBUF);
  bf16_t* chunk1  = (bf16_t*)(wsb + oCHUNK1);
  float*  covpart = (float*)(wsb + oCOVPART);
  float*  qkpart  = (float*)(wsb + oQKPART);
  bf16_t* gated   = (bf16_t*)(wsb + oGATED);
  bf16_t* dbuf    = (bf16_t*)(wsb + oDBUF);
  bf16_t* x1b     = (bf16_t*)(wsb + oX1B);
  bf16_t* y0c     = (bf16_t*)(wsb + oY0C);
  bf16_t* zbuf    = (bf16_t*)(wsb + oZ);

  const int GX = HWc / 128;  // 288 l-tiles
  const int NOS = 1 << 30;   // "no osplit"
  dim3 gA(GX, BN_);

  // 1. LN1: xn = LN(x)
  k_ln<float><<<(BN_ * HWc + TPB - 1) / TPB, TPB, 0, stream>>>(x, ln1_w, ln1_b, xn);

  // 2+3. qkv = dw3(c1x1(xn, w_qkv)) in 2 chunks of 192 channels
  for (int ci = 0; ci < 2; ++ci) {
    int c0 = ci * 192;
    k_mgA<bf16_t, float, 128, 0><<<gA, TPB, 0, stream>>>(
        w_qkv + (size_t)c0 * CDIM, w_qkv, NOS, nullptr, xn, nullptr, chunk1,
        192, CDIM, 192, 0);
    long totG = (long)BN_ * 192 * (HWc / 8);
    k_dw3v<<<(unsigned)((totG + TPB - 1) / TPB), TPB, 0, stream>>>(
        chunk1, w_qkv_dw, qkv, 192, c0, C3, totG);
  }

  // 4-7. correlation sort
  k_mu<<<CDIM, TPB, 0, stream>>>(qkv, mu);
  k_cov3<<<CV3, TPB, 0, stream>>>(qkv, covpart);
  k_covred<<<(CDIM * CDIM + TPB - 1) / TPB, TPB, 0, stream>>>(covpart, mu, cov);
  k_rank<<<1, CDIM, 0, stream>>>(cov, idx);
  // 8. norms
  k_norms<<<dim3(CDIM, BN_, 2), TPB, 0, stream>>>(qkv, idx, normq, normk);

  // groups (xn dead from here -> qkpart overlays it)
  const int gsz[4]    = {16, 32, 32, 48};
  const int gstart[4] = {0, 16, 48, 80};
  const int abase[4]  = {0, 512, 2560, 4608};
  for (int gi = 0; gi < 4; ++gi) {
    int start = gstart[gi];
    const float* cw_w = (const float*)d_in[16 + 4 * gi];
    const float* cw_b = (const float*)d_in[17 + 4 * gi];
    const float* gw   = (const float*)d_in[18 + 4 * gi];
    const float* gb   = (const float*)d_in[19 + 4 * gi];
    float* attF = atts + abase[gi];
    int GG = gsz[gi] * gsz[gi];
    if (gsz[gi] == 16) {
      k_qk2<16><<<dim3(NL2, BN_), TPB, 0, stream>>>(qkv, idx, start, qkpart);
      k_qkred<<<(BN_ * GG + TPB - 1) / TPB, TPB, 0, stream>>>(qkpart, attraw, GG);
      k_inter<16><<<BN_, TPB, 0, stream>>>(attraw, normq, normk, start, temperature, gi,
                                           qv_cache, cw_w, cw_b, gw, gb, attF);
      k_av<16><<<dim3(HWc / 128, BN_), TPB, 0, stream>>>(qkv, idx, attF, normq, normk, start,
                                                         out_all, sbuf);
    } else if (gsz[gi] == 32) {
      k_qk2<32><<<dim3(NL2, BN_), TPB, 0, stream>>>(qkv, idx, start, qkpart);
      k_qkred<<<(BN_ * GG + TPB - 1) / TPB, TPB, 0, stream>>>(qkpart, attraw, GG);
      k_inter<32><<<BN_, TPB, 0, stream>>>(attraw, normq, normk, start, temperature, gi,
                                           qv_cache, cw_w, cw_b, gw, gb, attF);
      k_av<32><<<dim3(HWc / 128, BN_), TPB, 0, stream>>>(qkv, idx, attF, normq, normk, start,
                                                         out_all, sbuf);
    } else {
      k_qk2<48><<<dim3(NL2, BN_), TPB, 0, stream>>>(qkv, idx, start, qkpart);
      k_qkred<<<(BN_ * GG + TPB - 1) / TPB, TPB, 0, stream>>>(qkpart, attraw, GG);
      k_inter<48><<<BN_, TPB, 0, stream>>>(attraw, normq, normk, start, temperature, gi,
                                           qv_cache, cw_w, cw_b, gw, gb, attF);
      k_av<48><<<dim3(HWc / 128, BN_), TPB, 0, stream>>>(qkv, idx, attF, normq, normk, start,
                                                         out_all, sbuf);
    }
  }
  // qv_new
  k_qvnew<<<(CDIM * CDIM + TPB - 1) / TPB, TPB, 0, stream>>>(atts, qv_cache, out_qv);

  // gated channel-MLP (qkv dead from here)
  k_mgA<bf16_t, bf16_t, 128, 2><<<gA, TPB, 0, stream>>>(
      intra_gate_w, intra_gate_w, NOS, intra_gate_b, sbuf, sbuf, gated,
      CDIM, CDIM, CDIM, CDIM);
  k_mgA<bf16_t, float, 128, 0><<<gA, TPB, 0, stream>>>(
      intra_down_w, intra_down_w, NOS, intra_down_b, gated, nullptr, dbuf,
      CDIM / 2, CDIM, CDIM / 2, 0);
  k_mgA<bf16_t, bf16_t, 64, 1><<<gA, TPB, 0, stream>>>(
      intra_up_w, intra_up_w, NOS, intra_up_b, dbuf, out_all, out_all,
      CDIM, CDIM / 2, CDIM, CDIM);
  // x1b = bf16(x + proj(out_all))
  k_mgA<bf16_t, float, 128, 1><<<gA, TPB, 0, stream>>>(
      w_proj, w_proj, NOS, nullptr, out_all, x, x1b, CDIM, CDIM, CDIM, CDIM);
  // LN2: xn2 = LN(x1b)
  k_ln<bf16_t><<<(BN_ * HWc + TPB - 1) / TPB, TPB, 0, stream>>>(x1b, ln2_w, ln2_b, xn2);

  // FFN in 4 chunks of 85 channel-pairs; y1+y2 in ONE dispatch via dual-W (osplit=85)
  for (int ci = 0; ci < 4; ++ci) {
    int c0 = ci * 85;
    k_mgA<bf16_t, float, 128, 0><<<gA, TPB, 0, stream>>>(
        ffn_in_w + (size_t)c0 * CDIM, ffn_in_w + (size_t)(HID + c0) * CDIM, 85,
        nullptr, xn2, nullptr, y0c, 170, CDIM, 170, 0);
    long totG = (long)BN_ * 85 * (HWc / 8);
    k_dwgeluv<<<(unsigned)((totG + TPB - 1) / TPB), TPB, 0, stream>>>(
        y0c, ffn_dw_w, zbuf, 85, c0, totG);
  }
  // out = x1b + c1x1(z, ffn_out_w)  (K=340, O=128 resident)
  k_mgB<float, bf16_t, 1><<<gA, TPB, 0, stream>>>(
      ffn_out_w, nullptr, zbuf, x1b, out, CDIM, HID, HID, CDIM, CDIM);
}